// Round 1
// baseline (535.794 us; speedup 1.0000x reference)
//
#include <hip/hip_runtime.h>

#define NSZ 128
#define NS3 (NSZ * NSZ * NSZ)

// ---------- small helpers ----------

__device__ __forceinline__ void inv3x3(const float* __restrict__ c, float* inv) {
    float a00 = c[0], a01 = c[1], a02 = c[2];
    float a10 = c[3], a11 = c[4], a12 = c[5];
    float a20 = c[6], a21 = c[7], a22 = c[8];
    float det = a00 * (a11 * a22 - a12 * a21)
              - a01 * (a10 * a22 - a12 * a20)
              + a02 * (a10 * a21 - a11 * a20);
    float id = 1.0f / det;
    inv[0] = (a11 * a22 - a12 * a21) * id;
    inv[1] = (a02 * a21 - a01 * a22) * id;
    inv[2] = (a01 * a12 - a02 * a11) * id;
    inv[3] = (a12 * a20 - a10 * a22) * id;
    inv[4] = (a00 * a22 - a02 * a20) * id;
    inv[5] = (a02 * a10 - a00 * a12) * id;
    inv[6] = (a10 * a21 - a11 * a20) * id;
    inv[7] = (a01 * a20 - a00 * a21) * id;
    inv[8] = (a00 * a11 - a01 * a10) * id;
}

__device__ __forceinline__ float det3x3(const float* __restrict__ c) {
    return c[0] * (c[4] * c[8] - c[5] * c[7])
         - c[1] * (c[3] * c[8] - c[5] * c[6])
         + c[2] * (c[3] * c[7] - c[4] * c[6]);
}

// Per-atom P3M order-4 stencil: indices (wrapped) and separable weights.
__device__ __forceinline__ void stencil_atom(const float* __restrict__ pos,
                                             const float* __restrict__ cell,
                                             int a,
                                             int ix[4], int iy[4], int iz[4],
                                             float wx[4], float wy[4], float wz[4]) {
    float inv[9];
    inv3x3(cell, inv);
    float px = pos[a * 3 + 0], py = pos[a * 3 + 1], pz = pos[a * 3 + 2];
    float pr[3];
    pr[0] = (float)NSZ * (px * inv[0] + py * inv[3] + pz * inv[6]);
    pr[1] = (float)NSZ * (px * inv[1] + py * inv[4] + pz * inv[7]);
    pr[2] = (float)NSZ * (px * inv[2] + py * inv[5] + pz * inv[8]);
    int base[3];
    float w[3][4];
#pragma unroll
    for (int d = 0; d < 3; d++) {
        float b = floorf(pr[d]);
        float x = pr[d] - b - 0.5f;
        float x2 = x * x, x3 = x2 * x;
        w[d][0] = (1.0f - 6.0f * x + 12.0f * x2 - 8.0f * x3) * (1.0f / 48.0f);
        w[d][1] = (23.0f - 30.0f * x - 12.0f * x2 + 24.0f * x3) * (1.0f / 48.0f);
        w[d][2] = (23.0f + 30.0f * x - 12.0f * x2 - 24.0f * x3) * (1.0f / 48.0f);
        w[d][3] = (1.0f + 6.0f * x + 12.0f * x2 + 8.0f * x3) * (1.0f / 48.0f);
        base[d] = (int)b;
    }
#pragma unroll
    for (int s = 0; s < 4; s++) {
        ix[s] = (base[0] + s - 1 + NSZ) & (NSZ - 1);
        iy[s] = (base[1] + s - 1 + NSZ) & (NSZ - 1);
        iz[s] = (base[2] + s - 1 + NSZ) & (NSZ - 1);
        wx[s] = w[0][s]; wy[s] = w[1][s]; wz[s] = w[2][s];
    }
}

// ---------- scatter: charges -> complex mesh (ch0=real, ch1=imag) ----------

__global__ void scatter_kernel(const float* __restrict__ pos,
                               const float* __restrict__ cell,
                               const int* __restrict__ species,
                               float* __restrict__ meshf,  // interleaved float2
                               int n_atoms) {
    int a = blockIdx.x * blockDim.x + threadIdx.x;
    if (a >= n_atoms) return;
    int ix[4], iy[4], iz[4];
    float wx[4], wy[4], wz[4];
    stencil_atom(pos, cell, a, ix, iy, iz, wx, wy, wz);
    int sp = species[a] & 1;  // 0 -> real slot, 1 -> imag slot
#pragma unroll
    for (int l = 0; l < 4; l++) {
        float wl = wx[l];
#pragma unroll
        for (int m = 0; m < 4; m++) {
            float wlm = wl * wy[m];
            int rowbase = (ix[l] * NSZ + iy[m]) * NSZ;
#pragma unroll
            for (int n = 0; n < 4; n++) {
                atomicAdd(meshf + (((size_t)(rowbase + iz[n])) << 1) + sp, wlm * wz[n]);
            }
        }
    }
}

// ---------- 128-point radix-2 FFT along one axis, one wave per line ----------

__device__ __forceinline__ int brev7(int i) { return (int)(__brev((unsigned)i) >> 25); }

template <int DIR>  // DIR = -1 forward, +1 inverse (both unnormalized)
__global__ void fft_pass(float2* __restrict__ data, int S, int SA, int SB) {
    __shared__ float2 lds[NSZ];
    int a = blockIdx.x, b = blockIdx.y;
    size_t start = (size_t)a * SA + (size_t)b * SB;
    int t = threadIdx.x;  // 64 threads
    float2 v0 = data[start + (size_t)t * S];
    float2 v1 = data[start + (size_t)(t + 64) * S];
    lds[brev7(t)] = v0;
    lds[brev7(t + 64)] = v1;
    __syncthreads();
#pragma unroll
    for (int s = 0; s < 7; s++) {
        int half = 1 << s;
        int pos = t & (half - 1);
        int i0 = ((t >> s) << (s + 1)) + pos;
        int i1 = i0 + half;
        // DIT twiddle: exp(DIR * 2*pi*i * pos / (2*half))
        float ang = (float)DIR * 6.283185307179586f * (float)pos / (float)(half * 2);
        float sw, cw;
        __sincosf(ang, &sw, &cw);
        float2 x0 = lds[i0], x1 = lds[i1];
        float2 tw = make_float2(x1.x * cw - x1.y * sw, x1.x * sw + x1.y * cw);
        lds[i0] = make_float2(x0.x + tw.x, x0.y + tw.y);
        lds[i1] = make_float2(x0.x - tw.x, x0.y - tw.y);
        __syncthreads();
    }
    data[start + (size_t)t * S] = lds[t];
    data[start + (size_t)(t + 64) * S] = lds[t + 64];
}

// ---------- multiply by G(k)/V in frequency space ----------

__global__ void gmul_kernel(float2* __restrict__ data, const float* __restrict__ cell,
                            float smearing) {
    int idx = blockIdx.x * blockDim.x + threadIdx.x;
    if (idx >= NS3) return;
    int kz = idx & (NSZ - 1);
    int ky = (idx >> 7) & (NSZ - 1);
    int kx = idx >> 14;
    float fx = (kx < NSZ / 2) ? (float)kx : (float)(kx - NSZ);
    float fy = (ky < NSZ / 2) ? (float)ky : (float)(ky - NSZ);
    float fz = (kz < NSZ / 2) ? (float)kz : (float)(kz - NSZ);
    float inv[9];
    inv3x3(cell, inv);
    const float twopi = 6.283185307179586f;
    // k_i = 2*pi * sum_j f_j * inv[i][j]
    float k0 = twopi * (fx * inv[0] + fy * inv[1] + fz * inv[2]);
    float k1 = twopi * (fx * inv[3] + fy * inv[4] + fz * inv[5]);
    float k2 = twopi * (fx * inv[6] + fy * inv[7] + fz * inv[8]);
    float ksq = k0 * k0 + k1 * k1 + k2 * k2;
    float vol = fabsf(det3x3(cell));
    float g = 0.0f;
    if (ksq > 0.0f) {
        g = 12.566370614359172f * __expf(-0.5f * smearing * smearing * ksq) / ksq;
    }
    g /= vol;
    float2 v = data[idx];
    data[idx] = make_float2(v.x * g, v.y * g);
}

// ---------- gather: mesh -> per-atom potential (2 channels) ----------

__global__ void gather_kernel(const float* __restrict__ pos,
                              const float* __restrict__ cell,
                              const float2* __restrict__ mesh,
                              float* __restrict__ out,
                              int n_atoms) {
    int a = blockIdx.x * blockDim.x + threadIdx.x;
    if (a >= n_atoms) return;
    int ix[4], iy[4], iz[4];
    float wx[4], wy[4], wz[4];
    stencil_atom(pos, cell, a, ix, iy, iz, wx, wy, wz);
    float acc0 = 0.0f, acc1 = 0.0f;
#pragma unroll
    for (int l = 0; l < 4; l++) {
        float wl = wx[l];
#pragma unroll
        for (int m = 0; m < 4; m++) {
            float wlm = wl * wy[m];
            int rowbase = (ix[l] * NSZ + iy[m]) * NSZ;
#pragma unroll
            for (int n = 0; n < 4; n++) {
                float2 v = mesh[rowbase + iz[n]];
                float ww = wlm * wz[n];
                acc0 += ww * v.x;
                acc1 += ww * v.y;
            }
        }
    }
    out[(size_t)a * 2 + 0] = acc0;
    out[(size_t)a * 2 + 1] = acc1;
}

// ---------- launch ----------

extern "C" void kernel_launch(void* const* d_in, const int* in_sizes, int n_in,
                              void* d_out, int out_size, void* d_ws, size_t ws_size,
                              hipStream_t stream) {
    const float* pos     = (const float*)d_in[0];
    const float* cell    = (const float*)d_in[1];
    const int*   species = (const int*)d_in[2];
    int n_atoms = in_sizes[0] / 3;

    float2* mesh = (float2*)d_ws;  // 128^3 complex = 16 MiB

    hipMemsetAsync(mesh, 0, (size_t)NS3 * sizeof(float2), stream);

    int ab = (n_atoms + 255) / 256;
    scatter_kernel<<<ab, 256, 0, stream>>>(pos, cell, species, (float*)mesh, n_atoms);

    dim3 g(NSZ, NSZ);
    // forward: z, y, x
    fft_pass<-1><<<g, 64, 0, stream>>>(mesh, 1,         NSZ * NSZ, NSZ);
    fft_pass<-1><<<g, 64, 0, stream>>>(mesh, NSZ,       NSZ * NSZ, 1);
    fft_pass<-1><<<g, 64, 0, stream>>>(mesh, NSZ * NSZ, NSZ,       1);

    gmul_kernel<<<NS3 / 256, 256, 0, stream>>>(mesh, cell, 1.0f /* SMEARING */);

    // inverse: x, y, z
    fft_pass<1><<<g, 64, 0, stream>>>(mesh, NSZ * NSZ, NSZ,       1);
    fft_pass<1><<<g, 64, 0, stream>>>(mesh, NSZ,       NSZ * NSZ, 1);
    fft_pass<1><<<g, 64, 0, stream>>>(mesh, 1,         NSZ * NSZ, NSZ);

    gather_kernel<<<ab, 256, 0, stream>>>(pos, cell, mesh, (float*)d_out, n_atoms);
}

// Round 2
// 325.192 us; speedup vs baseline: 1.6476x; 1.6476x over previous
//
#include <hip/hip_runtime.h>

#define NSZ 128
#define NS3 (NSZ * NSZ * NSZ)
#define NBUCK_D 16           // buckets per dim (bucket = 8^3 cells)
#define NBUCK (NBUCK_D * NBUCK_D * NBUCK_D)
#define REG 11               // region width = 8 + 3 (order-4 stencil halo)
#define REG3 (REG * REG * REG)

// ---------- small helpers ----------

__device__ __forceinline__ void inv3x3(const float* __restrict__ c, float* inv) {
    float a00 = c[0], a01 = c[1], a02 = c[2];
    float a10 = c[3], a11 = c[4], a12 = c[5];
    float a20 = c[6], a21 = c[7], a22 = c[8];
    float det = a00 * (a11 * a22 - a12 * a21)
              - a01 * (a10 * a22 - a12 * a20)
              + a02 * (a10 * a21 - a11 * a20);
    float id = 1.0f / det;
    inv[0] = (a11 * a22 - a12 * a21) * id;
    inv[1] = (a02 * a21 - a01 * a22) * id;
    inv[2] = (a01 * a12 - a02 * a11) * id;
    inv[3] = (a12 * a20 - a10 * a22) * id;
    inv[4] = (a00 * a22 - a02 * a20) * id;
    inv[5] = (a02 * a10 - a00 * a12) * id;
    inv[6] = (a10 * a21 - a11 * a20) * id;
    inv[7] = (a01 * a20 - a00 * a21) * id;
    inv[8] = (a00 * a11 - a01 * a10) * id;
}

__device__ __forceinline__ float det3x3(const float* __restrict__ c) {
    return c[0] * (c[4] * c[8] - c[5] * c[7])
         - c[1] * (c[3] * c[8] - c[5] * c[6])
         + c[2] * (c[3] * c[7] - c[4] * c[6]);
}

// Raw (unwrapped) order-4 stencil: base cell (clamped to [0,127]) + weights.
__device__ __forceinline__ void stencil_raw(const float* __restrict__ pos,
                                            const float* __restrict__ cell,
                                            int a, int base[3], float w[3][4]) {
    float inv[9];
    inv3x3(cell, inv);
    float px = pos[a * 3 + 0], py = pos[a * 3 + 1], pz = pos[a * 3 + 2];
    float pr[3];
    pr[0] = (float)NSZ * (px * inv[0] + py * inv[3] + pz * inv[6]);
    pr[1] = (float)NSZ * (px * inv[1] + py * inv[4] + pz * inv[7]);
    pr[2] = (float)NSZ * (px * inv[2] + py * inv[5] + pz * inv[8]);
#pragma unroll
    for (int d = 0; d < 3; d++) {
        float b = floorf(pr[d]);
        float x = pr[d] - b - 0.5f;
        float x2 = x * x, x3 = x2 * x;
        w[d][0] = (1.0f - 6.0f * x + 12.0f * x2 - 8.0f * x3) * (1.0f / 48.0f);
        w[d][1] = (23.0f - 30.0f * x - 12.0f * x2 + 24.0f * x3) * (1.0f / 48.0f);
        w[d][2] = (23.0f + 30.0f * x - 12.0f * x2 - 24.0f * x3) * (1.0f / 48.0f);
        w[d][3] = (1.0f + 6.0f * x + 12.0f * x2 + 8.0f * x3) * (1.0f / 48.0f);
        int bi = (int)b;
        base[d] = bi < 0 ? 0 : (bi > NSZ - 1 ? NSZ - 1 : bi);
    }
}

// ---------- binning ----------

__global__ void bin_hist(const float* __restrict__ pos, const float* __restrict__ cell,
                         int* __restrict__ counts, int* __restrict__ ba, int n_atoms) {
    int a = blockIdx.x * blockDim.x + threadIdx.x;
    if (a >= n_atoms) return;
    int base[3];
    float w[3][4];
    stencil_raw(pos, cell, a, base, w);
    int bucket = ((base[0] >> 3) * NBUCK_D + (base[1] >> 3)) * NBUCK_D + (base[2] >> 3);
    ba[a] = bucket;
    atomicAdd(&counts[bucket], 1);
}

__global__ void __launch_bounds__(1024)
scan4096(const int* __restrict__ counts, int* __restrict__ starts, int* __restrict__ cursor) {
    __shared__ int sd[1024];
    int t = threadIdx.x;
    int c0 = counts[4 * t], c1 = counts[4 * t + 1], c2 = counts[4 * t + 2], c3 = counts[4 * t + 3];
    int s1 = c0, s2 = c0 + c1, s3 = c0 + c1 + c2, tot = c0 + c1 + c2 + c3;
    sd[t] = tot;
    __syncthreads();
    for (int off = 1; off < 1024; off <<= 1) {
        int v = (t >= off) ? sd[t - off] : 0;
        __syncthreads();
        sd[t] += v;
        __syncthreads();
    }
    int ex = sd[t] - tot;
    starts[4 * t]     = ex;      cursor[4 * t]     = ex;
    starts[4 * t + 1] = ex + s1; cursor[4 * t + 1] = ex + s1;
    starts[4 * t + 2] = ex + s2; cursor[4 * t + 2] = ex + s2;
    starts[4 * t + 3] = ex + s3; cursor[4 * t + 3] = ex + s3;
    if (t == 1023) starts[4096] = sd[1023];
}

__global__ void bin_permute(const int* __restrict__ ba, int* __restrict__ cursor,
                            int* __restrict__ perm, int n_atoms) {
    int a = blockIdx.x * blockDim.x + threadIdx.x;
    if (a >= n_atoms) return;
    int p = atomicAdd(&cursor[ba[a]], 1);
    perm[p] = a;
}

// ---------- binned 8-color scatter: LDS accumulation, plain global RMW ----------

__global__ void __launch_bounds__(256)
scatter_binned(const float* __restrict__ pos, const float* __restrict__ cell,
               const int* __restrict__ species, const int* __restrict__ starts,
               const int* __restrict__ perm, float2* __restrict__ mesh,
               int cx, int cy, int cz) {
    __shared__ float acc[REG3 * 2];
    int bx = blockIdx.x * 2 + cx, by = blockIdx.y * 2 + cy, bz = blockIdx.z * 2 + cz;
    int bucket = (bx * NBUCK_D + by) * NBUCK_D + bz;
    int s = starts[bucket], e = starts[bucket + 1];
    if (s == e) return;
    int t = threadIdx.x;
    for (int i = t; i < REG3 * 2; i += 256) acc[i] = 0.0f;
    __syncthreads();

    int sub = t & 3;  // which l-plane of the stencil this thread handles
    for (int i = s + (t >> 2); i < e; i += 64) {
        int a = perm[i];
        int base[3];
        float w[3][4];
        stencil_raw(pos, cell, a, base, w);
        int sp = species[a] & 1;
        int rx = base[0] - bx * 8 + sub;           // in [0, 10]
        float wl = w[0][sub];
        int ry0 = base[1] - by * 8;
        int rz0 = base[2] - bz * 8;
#pragma unroll
        for (int m = 0; m < 4; m++) {
            float wlm = wl * w[1][m];
            int rowb = ((rx * REG) + (ry0 + m)) * REG + rz0;
#pragma unroll
            for (int n = 0; n < 4; n++) {
                atomicAdd(&acc[(rowb + n) * 2 + sp], wlm * w[2][n]);
            }
        }
    }
    __syncthreads();

    int ox = bx * 8 - 1, oy = by * 8 - 1, oz = bz * 8 - 1;
    for (int i = t; i < REG3; i += 256) {
        int rx = i / (REG * REG);
        int rem = i % (REG * REG);
        int ry = rem / REG, rz = rem % REG;
        int gx = (ox + rx + NSZ) & (NSZ - 1);
        int gy = (oy + ry + NSZ) & (NSZ - 1);
        int gz = (oz + rz + NSZ) & (NSZ - 1);
        size_t gi = (size_t)(gx * NSZ + gy) * NSZ + gz;
        float2 v = mesh[gi];
        v.x += acc[i * 2];
        v.y += acc[i * 2 + 1];
        mesh[gi] = v;
    }
}

// ---------- fallback atomic scatter (if ws too small) ----------

__global__ void scatter_atomic(const float* __restrict__ pos,
                               const float* __restrict__ cell,
                               const int* __restrict__ species,
                               float* __restrict__ meshf, int n_atoms) {
    int a = blockIdx.x * blockDim.x + threadIdx.x;
    if (a >= n_atoms) return;
    int base[3];
    float w[3][4];
    stencil_raw(pos, cell, a, base, w);
    int sp = species[a] & 1;
#pragma unroll
    for (int l = 0; l < 4; l++) {
        int gx = (base[0] + l - 1 + NSZ) & (NSZ - 1);
#pragma unroll
        for (int m = 0; m < 4; m++) {
            int gy = (base[1] + m - 1 + NSZ) & (NSZ - 1);
            float wlm = w[0][l] * w[1][m];
            int rowb = (gx * NSZ + gy) * NSZ;
#pragma unroll
            for (int n = 0; n < 4; n++) {
                int gz = (base[2] + n - 1 + NSZ) & (NSZ - 1);
                atomicAdd(meshf + (((size_t)(rowb + gz)) << 1) + sp, wlm * w[2][n]);
            }
        }
    }
}

// ---------- 128-point radix-2 FFT along one axis, one wave per line ----------

__device__ __forceinline__ int brev7(int i) { return (int)(__brev((unsigned)i) >> 25); }

template <int DIR>  // DIR = -1 forward, +1 inverse (both unnormalized)
__global__ void fft_pass(float2* __restrict__ data, int S, int SA, int SB) {
    __shared__ float2 lds[NSZ];
    int a = blockIdx.x, b = blockIdx.y;
    size_t start = (size_t)a * SA + (size_t)b * SB;
    int t = threadIdx.x;  // 64 threads
    float2 v0 = data[start + (size_t)t * S];
    float2 v1 = data[start + (size_t)(t + 64) * S];
    lds[brev7(t)] = v0;
    lds[brev7(t + 64)] = v1;
    __syncthreads();
#pragma unroll
    for (int s = 0; s < 7; s++) {
        int half = 1 << s;
        int pos = t & (half - 1);
        int i0 = ((t >> s) << (s + 1)) + pos;
        int i1 = i0 + half;
        float ang = (float)DIR * 6.283185307179586f * (float)pos / (float)(half * 2);
        float sw, cw;
        __sincosf(ang, &sw, &cw);
        float2 x0 = lds[i0], x1 = lds[i1];
        float2 tw = make_float2(x1.x * cw - x1.y * sw, x1.x * sw + x1.y * cw);
        lds[i0] = make_float2(x0.x + tw.x, x0.y + tw.y);
        lds[i1] = make_float2(x0.x - tw.x, x0.y - tw.y);
        __syncthreads();
    }
    data[start + (size_t)t * S] = lds[t];
    data[start + (size_t)(t + 64) * S] = lds[t + 64];
}

// ---------- multiply by G(k)/V in frequency space ----------

__global__ void gmul_kernel(float2* __restrict__ data, const float* __restrict__ cell,
                            float smearing) {
    int idx = blockIdx.x * blockDim.x + threadIdx.x;
    if (idx >= NS3) return;
    int kz = idx & (NSZ - 1);
    int ky = (idx >> 7) & (NSZ - 1);
    int kx = idx >> 14;
    float fx = (kx < NSZ / 2) ? (float)kx : (float)(kx - NSZ);
    float fy = (ky < NSZ / 2) ? (float)ky : (float)(ky - NSZ);
    float fz = (kz < NSZ / 2) ? (float)kz : (float)(kz - NSZ);
    float inv[9];
    inv3x3(cell, inv);
    const float twopi = 6.283185307179586f;
    float k0 = twopi * (fx * inv[0] + fy * inv[1] + fz * inv[2]);
    float k1 = twopi * (fx * inv[3] + fy * inv[4] + fz * inv[5]);
    float k2 = twopi * (fx * inv[6] + fy * inv[7] + fz * inv[8]);
    float ksq = k0 * k0 + k1 * k1 + k2 * k2;
    float vol = fabsf(det3x3(cell));
    float g = 0.0f;
    if (ksq > 0.0f) {
        g = 12.566370614359172f * __expf(-0.5f * smearing * smearing * ksq) / ksq;
    }
    g /= vol;
    float2 v = data[idx];
    data[idx] = make_float2(v.x * g, v.y * g);
}

// ---------- gather: mesh -> per-atom potential (2 channels) ----------

__global__ void gather_kernel(const float* __restrict__ pos,
                              const float* __restrict__ cell,
                              const float2* __restrict__ mesh,
                              float* __restrict__ out,
                              int n_atoms) {
    int a = blockIdx.x * blockDim.x + threadIdx.x;
    if (a >= n_atoms) return;
    int base[3];
    float w[3][4];
    stencil_raw(pos, cell, a, base, w);
    float acc0 = 0.0f, acc1 = 0.0f;
#pragma unroll
    for (int l = 0; l < 4; l++) {
        int gx = (base[0] + l - 1 + NSZ) & (NSZ - 1);
#pragma unroll
        for (int m = 0; m < 4; m++) {
            int gy = (base[1] + m - 1 + NSZ) & (NSZ - 1);
            float wlm = w[0][l] * w[1][m];
            int rowb = (gx * NSZ + gy) * NSZ;
#pragma unroll
            for (int n = 0; n < 4; n++) {
                int gz = (base[2] + n - 1 + NSZ) & (NSZ - 1);
                float2 v = mesh[rowb + gz];
                float ww = wlm * w[2][n];
                acc0 += ww * v.x;
                acc1 += ww * v.y;
            }
        }
    }
    out[(size_t)a * 2 + 0] = acc0;
    out[(size_t)a * 2 + 1] = acc1;
}

// ---------- launch ----------

extern "C" void kernel_launch(void* const* d_in, const int* in_sizes, int n_in,
                              void* d_out, int out_size, void* d_ws, size_t ws_size,
                              hipStream_t stream) {
    const float* pos     = (const float*)d_in[0];
    const float* cell    = (const float*)d_in[1];
    const int*   species = (const int*)d_in[2];
    int n_atoms = in_sizes[0] / 3;

    // workspace layout
    char* ws = (char*)d_ws;
    float2* mesh = (float2*)ws;                                   // 16 MiB
    size_t off = (size_t)NS3 * sizeof(float2);
    int* counts = (int*)(ws + off);           off += NBUCK * 4;   // 16 KiB
    int* starts = (int*)(ws + off);           off += (NBUCK + 4) * 4;
    int* cursor = (int*)(ws + off);           off += NBUCK * 4;
    int* ba     = (int*)(ws + off);           off += (size_t)n_atoms * 4;
    int* perm   = (int*)(ws + off);           off += (size_t)n_atoms * 4;
    bool binned = (ws_size >= off);

    int ab = (n_atoms + 255) / 256;

    if (binned) {
        // zero mesh + counts in one async memset
        hipMemsetAsync(ws, 0, (size_t)NS3 * sizeof(float2) + NBUCK * 4, stream);
        bin_hist<<<ab, 256, 0, stream>>>(pos, cell, counts, ba, n_atoms);
        scan4096<<<1, 1024, 0, stream>>>(counts, starts, cursor);
        bin_permute<<<ab, 256, 0, stream>>>(ba, cursor, perm, n_atoms);
        dim3 cg(NBUCK_D / 2, NBUCK_D / 2, NBUCK_D / 2);
        for (int c = 0; c < 8; c++) {
            scatter_binned<<<cg, 256, 0, stream>>>(pos, cell, species, starts, perm,
                                                   mesh, (c >> 2) & 1, (c >> 1) & 1, c & 1);
        }
    } else {
        hipMemsetAsync(mesh, 0, (size_t)NS3 * sizeof(float2), stream);
        scatter_atomic<<<ab, 256, 0, stream>>>(pos, cell, species, (float*)mesh, n_atoms);
    }

    dim3 g(NSZ, NSZ);
    // forward: z, y, x
    fft_pass<-1><<<g, 64, 0, stream>>>(mesh, 1,         NSZ * NSZ, NSZ);
    fft_pass<-1><<<g, 64, 0, stream>>>(mesh, NSZ,       NSZ * NSZ, 1);
    fft_pass<-1><<<g, 64, 0, stream>>>(mesh, NSZ * NSZ, NSZ,       1);

    gmul_kernel<<<NS3 / 256, 256, 0, stream>>>(mesh, cell, 1.0f /* SMEARING */);

    // inverse: x, y, z
    fft_pass<1><<<g, 64, 0, stream>>>(mesh, NSZ * NSZ, NSZ,       1);
    fft_pass<1><<<g, 64, 0, stream>>>(mesh, NSZ,       NSZ * NSZ, 1);
    fft_pass<1><<<g, 64, 0, stream>>>(mesh, 1,         NSZ * NSZ, NSZ);

    gather_kernel<<<ab, 256, 0, stream>>>(pos, cell, mesh, (float*)d_out, n_atoms);
}

// Round 3
// 285.287 us; speedup vs baseline: 1.8781x; 1.1399x over previous
//
#include <hip/hip_runtime.h>

#define NSZ 128
#define NS3 (NSZ * NSZ * NSZ)
#define NBUCK_D 16           // buckets per dim (bucket = 8^3 cells)
#define NBUCK (NBUCK_D * NBUCK_D * NBUCK_D)
#define REG 11               // region width = 8 + 3 (order-4 stencil halo)
#define REG3 (REG * REG * REG)
#define LROW 129             // padded LDS row stride (complex) -> <=4-way bank aliasing
#define LDS_BYTES (NSZ * LROW * sizeof(float2))   // 132096

// ---------- small helpers ----------

__device__ __forceinline__ void inv3x3(const float* __restrict__ c, float* inv) {
    float a00 = c[0], a01 = c[1], a02 = c[2];
    float a10 = c[3], a11 = c[4], a12 = c[5];
    float a20 = c[6], a21 = c[7], a22 = c[8];
    float det = a00 * (a11 * a22 - a12 * a21)
              - a01 * (a10 * a22 - a12 * a20)
              + a02 * (a10 * a21 - a11 * a20);
    float id = 1.0f / det;
    inv[0] = (a11 * a22 - a12 * a21) * id;
    inv[1] = (a02 * a21 - a01 * a22) * id;
    inv[2] = (a01 * a12 - a02 * a11) * id;
    inv[3] = (a12 * a20 - a10 * a22) * id;
    inv[4] = (a00 * a22 - a02 * a20) * id;
    inv[5] = (a02 * a10 - a00 * a12) * id;
    inv[6] = (a10 * a21 - a11 * a20) * id;
    inv[7] = (a01 * a20 - a00 * a21) * id;
    inv[8] = (a00 * a11 - a01 * a10) * id;
}

__device__ __forceinline__ float det3x3(const float* __restrict__ c) {
    return c[0] * (c[4] * c[8] - c[5] * c[7])
         - c[1] * (c[3] * c[8] - c[5] * c[6])
         + c[2] * (c[3] * c[7] - c[4] * c[6]);
}

__device__ __forceinline__ int brev7(int i) { return (int)(__brev((unsigned)i) >> 25); }

__device__ __forceinline__ float2 cadd(float2 a, float2 b) { return make_float2(a.x + b.x, a.y + b.y); }
__device__ __forceinline__ float2 csub(float2 a, float2 b) { return make_float2(a.x - b.x, a.y - b.y); }
__device__ __forceinline__ float2 cmul(float2 a, float2 b) {
    return make_float2(a.x * b.x - a.y * b.y, a.x * b.y + a.y * b.x);
}
__device__ __forceinline__ float2 cmulc(float2 a, float2 b) {  // a * conj(b)
    return make_float2(a.x * b.x + a.y * b.y, a.y * b.x - a.x * b.y);
}

// Raw (unwrapped) order-4 stencil: base cell (clamped to [0,127]) + weights.
__device__ __forceinline__ void stencil_raw(const float* __restrict__ pos,
                                            const float* __restrict__ cell,
                                            int a, int base[3], float w[3][4]) {
    float inv[9];
    inv3x3(cell, inv);
    float px = pos[a * 3 + 0], py = pos[a * 3 + 1], pz = pos[a * 3 + 2];
    float pr[3];
    pr[0] = (float)NSZ * (px * inv[0] + py * inv[3] + pz * inv[6]);
    pr[1] = (float)NSZ * (px * inv[1] + py * inv[4] + pz * inv[7]);
    pr[2] = (float)NSZ * (px * inv[2] + py * inv[5] + pz * inv[8]);
#pragma unroll
    for (int d = 0; d < 3; d++) {
        float b = floorf(pr[d]);
        float x = pr[d] - b - 0.5f;
        float x2 = x * x, x3 = x2 * x;
        w[d][0] = (1.0f - 6.0f * x + 12.0f * x2 - 8.0f * x3) * (1.0f / 48.0f);
        w[d][1] = (23.0f - 30.0f * x - 12.0f * x2 + 24.0f * x3) * (1.0f / 48.0f);
        w[d][2] = (23.0f + 30.0f * x - 12.0f * x2 - 24.0f * x3) * (1.0f / 48.0f);
        w[d][3] = (1.0f + 6.0f * x + 12.0f * x2 + 8.0f * x3) * (1.0f / 48.0f);
        int bi = (int)b;
        base[d] = bi < 0 ? 0 : (bi > NSZ - 1 ? NSZ - 1 : bi);
    }
}

// ---------- binning ----------

__global__ void bin_hist(const float* __restrict__ pos, const float* __restrict__ cell,
                         int* __restrict__ counts, int* __restrict__ ba, int n_atoms) {
    int a = blockIdx.x * blockDim.x + threadIdx.x;
    if (a >= n_atoms) return;
    int base[3];
    float w[3][4];
    stencil_raw(pos, cell, a, base, w);
    int bucket = ((base[0] >> 3) * NBUCK_D + (base[1] >> 3)) * NBUCK_D + (base[2] >> 3);
    ba[a] = bucket;
    atomicAdd(&counts[bucket], 1);
}

__global__ void __launch_bounds__(1024)
scan4096(const int* __restrict__ counts, int* __restrict__ starts, int* __restrict__ cursor) {
    __shared__ int sd[1024];
    int t = threadIdx.x;
    int c0 = counts[4 * t], c1 = counts[4 * t + 1], c2 = counts[4 * t + 2], c3 = counts[4 * t + 3];
    int s1 = c0, s2 = c0 + c1, s3 = c0 + c1 + c2, tot = c0 + c1 + c2 + c3;
    sd[t] = tot;
    __syncthreads();
    for (int off = 1; off < 1024; off <<= 1) {
        int v = (t >= off) ? sd[t - off] : 0;
        __syncthreads();
        sd[t] += v;
        __syncthreads();
    }
    int ex = sd[t] - tot;
    starts[4 * t]     = ex;      cursor[4 * t]     = ex;
    starts[4 * t + 1] = ex + s1; cursor[4 * t + 1] = ex + s1;
    starts[4 * t + 2] = ex + s2; cursor[4 * t + 2] = ex + s2;
    starts[4 * t + 3] = ex + s3; cursor[4 * t + 3] = ex + s3;
    if (t == 1023) starts[4096] = sd[1023];
}

__global__ void bin_permute(const int* __restrict__ ba, int* __restrict__ cursor,
                            int* __restrict__ perm, int n_atoms) {
    int a = blockIdx.x * blockDim.x + threadIdx.x;
    if (a >= n_atoms) return;
    int p = atomicAdd(&cursor[ba[a]], 1);
    perm[p] = a;
}

// ---------- binned 8-color scatter: LDS accumulation, plain global RMW ----------

__global__ void __launch_bounds__(256)
scatter_binned(const float* __restrict__ pos, const float* __restrict__ cell,
               const int* __restrict__ species, const int* __restrict__ starts,
               const int* __restrict__ perm, float2* __restrict__ mesh,
               int cx, int cy, int cz) {
    __shared__ float acc[REG3 * 2];
    int bx = blockIdx.x * 2 + cx, by = blockIdx.y * 2 + cy, bz = blockIdx.z * 2 + cz;
    int bucket = (bx * NBUCK_D + by) * NBUCK_D + bz;
    int s = starts[bucket], e = starts[bucket + 1];
    if (s == e) return;
    int t = threadIdx.x;
    for (int i = t; i < REG3 * 2; i += 256) acc[i] = 0.0f;
    __syncthreads();

    int sub = t & 3;  // which l-plane of the stencil this thread handles
    for (int i = s + (t >> 2); i < e; i += 64) {
        int a = perm[i];
        int base[3];
        float w[3][4];
        stencil_raw(pos, cell, a, base, w);
        int sp = species[a] & 1;
        int rx = base[0] - bx * 8 + sub;           // in [0, 10]
        float wl = w[0][sub];
        int ry0 = base[1] - by * 8;
        int rz0 = base[2] - bz * 8;
#pragma unroll
        for (int m = 0; m < 4; m++) {
            float wlm = wl * w[1][m];
            int rowb = ((rx * REG) + (ry0 + m)) * REG + rz0;
#pragma unroll
            for (int n = 0; n < 4; n++) {
                atomicAdd(&acc[(rowb + n) * 2 + sp], wlm * w[2][n]);
            }
        }
    }
    __syncthreads();

    int ox = bx * 8 - 1, oy = by * 8 - 1, oz = bz * 8 - 1;
    for (int i = t; i < REG3; i += 256) {
        int rx = i / (REG * REG);
        int rem = i % (REG * REG);
        int ry = rem / REG, rz = rem % REG;
        int gx = (ox + rx + NSZ) & (NSZ - 1);
        int gy = (oy + ry + NSZ) & (NSZ - 1);
        int gz = (oz + rz + NSZ) & (NSZ - 1);
        size_t gi = (size_t)(gx * NSZ + gy) * NSZ + gz;
        float2 v = mesh[gi];
        v.x += acc[i * 2];
        v.y += acc[i * 2 + 1];
        mesh[gi] = v;
    }
}

// ---------- fallback atomic scatter (if ws too small) ----------

__global__ void scatter_atomic(const float* __restrict__ pos,
                               const float* __restrict__ cell,
                               const int* __restrict__ species,
                               float* __restrict__ meshf, int n_atoms) {
    int a = blockIdx.x * blockDim.x + threadIdx.x;
    if (a >= n_atoms) return;
    int base[3];
    float w[3][4];
    stencil_raw(pos, cell, a, base, w);
    int sp = species[a] & 1;
#pragma unroll
    for (int l = 0; l < 4; l++) {
        int gx = (base[0] + l - 1 + NSZ) & (NSZ - 1);
#pragma unroll
        for (int m = 0; m < 4; m++) {
            int gy = (base[1] + m - 1 + NSZ) & (NSZ - 1);
            float wlm = w[0][l] * w[1][m];
            int rowb = (gx * NSZ + gy) * NSZ;
#pragma unroll
        for (int n = 0; n < 4; n++) {
                int gz = (base[2] + n - 1 + NSZ) & (NSZ - 1);
                atomicAdd(meshf + (((size_t)(rowb + gz)) << 1) + sp, wlm * w[2][n]);
            }
        }
    }
}

// ---------- fused FFT kernels ----------
// Forward uses DIF (natural in -> bit-reversed out); inverse uses DIT
// (bit-reversed in -> natural out); G(k) indexed via brev7 of physical index.
// LDS plane padded to row stride LROW=129 complex.
// Twiddle LUT: tw[j] = exp(-2*pi*i*j/128), j=0..63 (forward); conj for inverse.

// A: per x-slab, forward z-FFT then y-FFT.
__global__ void __launch_bounds__(1024)
fft_fwd_zy(float2* __restrict__ mesh) {
    extern __shared__ float2 sl[];
    __shared__ float2 tw[64];
    int t = threadIdx.x;
    int xs = blockIdx.x;
    if (t < 64) {
        float sn, cs;
        __sincosf(6.283185307179586f * (float)t / 128.0f, &sn, &cs);
        tw[t] = make_float2(cs, -sn);
    }
    const float4* src = (const float4*)(mesh + (size_t)xs * (NSZ * NSZ));
    for (int f = t; f < 8192; f += 1024) {
        float4 v = src[f];
        int y = f >> 6, z = (f & 63) * 2;
        sl[y * LROW + z]     = make_float2(v.x, v.y);
        sl[y * LROW + z + 1] = make_float2(v.z, v.w);
    }
    __syncthreads();
    int lane = t & 127, jb = (t >> 7) * 8;
    // z-axis DIF (batch over y = lane)
    for (int s = 6; s >= 0; --s) {
        int half = 1 << s;
        for (int j = jb; j < jb + 8; ++j) {
            int pos = j & (half - 1);
            int i0 = ((j >> s) << (s + 1)) + pos;
            float2 w = tw[pos << (6 - s)];
            float2* p0 = &sl[lane * LROW + i0];
            float2 a = p0[0], b = p0[half];
            p0[0]    = cadd(a, b);
            p0[half] = cmul(csub(a, b), w);
        }
        __syncthreads();
    }
    // y-axis DIF (batch over z = lane)
    for (int s = 6; s >= 0; --s) {
        int half = 1 << s;
        for (int j = jb; j < jb + 8; ++j) {
            int pos = j & (half - 1);
            int i0 = ((j >> s) << (s + 1)) + pos;
            float2 w = tw[pos << (6 - s)];
            float2* p0 = &sl[i0 * LROW + lane];
            float2 a = p0[0], b = p0[half * LROW];
            p0[0]           = cadd(a, b);
            p0[half * LROW] = cmul(csub(a, b), w);
        }
        __syncthreads();
    }
    float4* dst = (float4*)(mesh + (size_t)xs * (NSZ * NSZ));
    for (int f = t; f < 8192; f += 1024) {
        int y = f >> 6, z = (f & 63) * 2;
        float2 u0 = sl[y * LROW + z], u1 = sl[y * LROW + z + 1];
        dst[f] = make_float4(u0.x, u0.y, u1.x, u1.y);
    }
}

// B: per y-plane, forward x-FFT, G multiply, inverse x-FFT.
__global__ void __launch_bounds__(1024)
fft_x_g(float2* __restrict__ mesh, const float* __restrict__ cell, float smearing) {
    extern __shared__ float2 sl[];
    __shared__ float2 tw[64];
    int t = threadIdx.x;
    int y = blockIdx.x;
    if (t < 64) {
        float sn, cs;
        __sincosf(6.283185307179586f * (float)t / 128.0f, &sn, &cs);
        tw[t] = make_float2(cs, -sn);
    }
    for (int f = t; f < 8192; f += 1024) {
        int x = f >> 6, c = f & 63;
        float4 v = ((const float4*)mesh)[(size_t)x * 8192 + (size_t)y * 64 + c];
        int z = c * 2;
        sl[x * LROW + z]     = make_float2(v.x, v.y);
        sl[x * LROW + z + 1] = make_float2(v.z, v.w);
    }
    __syncthreads();
    int lane = t & 127, jb = (t >> 7) * 8;
    // x-axis DIF (batch over z = lane)
    for (int s = 6; s >= 0; --s) {
        int half = 1 << s;
        for (int j = jb; j < jb + 8; ++j) {
            int pos = j & (half - 1);
            int i0 = ((j >> s) << (s + 1)) + pos;
            float2 w = tw[pos << (6 - s)];
            float2* p0 = &sl[i0 * LROW + lane];
            float2 a = p0[0], b = p0[half * LROW];
            p0[0]           = cadd(a, b);
            p0[half * LROW] = cmul(csub(a, b), w);
        }
        __syncthreads();
    }
    // G multiply (frequencies are brev7 of physical indices on all axes)
    {
        float inv[9];
        inv3x3(cell, inv);
        float vol = fabsf(det3x3(cell));
        int kyi = brev7(y);
        float fy = (kyi < NSZ / 2) ? (float)kyi : (float)(kyi - NSZ);
        const float twopi = 6.283185307179586f;
        for (int f = t; f < NSZ * NSZ; f += 1024) {
            int px = f >> 7, pz = f & 127;
            int kxi = brev7(px), kzi = brev7(pz);
            float fx = (kxi < NSZ / 2) ? (float)kxi : (float)(kxi - NSZ);
            float fz = (kzi < NSZ / 2) ? (float)kzi : (float)(kzi - NSZ);
            float k0 = twopi * (fx * inv[0] + fy * inv[1] + fz * inv[2]);
            float k1 = twopi * (fx * inv[3] + fy * inv[4] + fz * inv[5]);
            float k2 = twopi * (fx * inv[6] + fy * inv[7] + fz * inv[8]);
            float ksq = k0 * k0 + k1 * k1 + k2 * k2;
            float g = 0.0f;
            if (ksq > 0.0f) {
                g = 12.566370614359172f * __expf(-0.5f * smearing * smearing * ksq) / ksq;
            }
            g /= vol;
            float2 v = sl[px * LROW + pz];
            sl[px * LROW + pz] = make_float2(v.x * g, v.y * g);
        }
    }
    __syncthreads();
    // x-axis DIT inverse (batch over z = lane)
    for (int s = 0; s < 7; ++s) {
        int half = 1 << s;
        for (int j = jb; j < jb + 8; ++j) {
            int pos = j & (half - 1);
            int i0 = ((j >> s) << (s + 1)) + pos;
            float2 w = tw[pos << (6 - s)];
            float2* p0 = &sl[i0 * LROW + lane];
            float2 a = p0[0];
            float2 bw = cmulc(p0[half * LROW], w);
            p0[0]           = cadd(a, bw);
            p0[half * LROW] = csub(a, bw);
        }
        __syncthreads();
    }
    for (int f = t; f < 8192; f += 1024) {
        int x = f >> 6, c = f & 63;
        int z = c * 2;
        float2 u0 = sl[x * LROW + z], u1 = sl[x * LROW + z + 1];
        ((float4*)mesh)[(size_t)x * 8192 + (size_t)y * 64 + c] = make_float4(u0.x, u0.y, u1.x, u1.y);
    }
}

// C: per x-slab, inverse y-FFT then inverse z-FFT.
__global__ void __launch_bounds__(1024)
fft_inv_yz(float2* __restrict__ mesh) {
    extern __shared__ float2 sl[];
    __shared__ float2 tw[64];
    int t = threadIdx.x;
    int xs = blockIdx.x;
    if (t < 64) {
        float sn, cs;
        __sincosf(6.283185307179586f * (float)t / 128.0f, &sn, &cs);
        tw[t] = make_float2(cs, -sn);
    }
    const float4* src = (const float4*)(mesh + (size_t)xs * (NSZ * NSZ));
    for (int f = t; f < 8192; f += 1024) {
        float4 v = src[f];
        int y = f >> 6, z = (f & 63) * 2;
        sl[y * LROW + z]     = make_float2(v.x, v.y);
        sl[y * LROW + z + 1] = make_float2(v.z, v.w);
    }
    __syncthreads();
    int lane = t & 127, jb = (t >> 7) * 8;
    // y-axis DIT inverse (batch over z = lane)
    for (int s = 0; s < 7; ++s) {
        int half = 1 << s;
        for (int j = jb; j < jb + 8; ++j) {
            int pos = j & (half - 1);
            int i0 = ((j >> s) << (s + 1)) + pos;
            float2 w = tw[pos << (6 - s)];
            float2* p0 = &sl[i0 * LROW + lane];
            float2 a = p0[0];
            float2 bw = cmulc(p0[half * LROW], w);
            p0[0]           = cadd(a, bw);
            p0[half * LROW] = csub(a, bw);
        }
        __syncthreads();
    }
    // z-axis DIT inverse (batch over y = lane)
    for (int s = 0; s < 7; ++s) {
        int half = 1 << s;
        for (int j = jb; j < jb + 8; ++j) {
            int pos = j & (half - 1);
            int i0 = ((j >> s) << (s + 1)) + pos;
            float2 w = tw[pos << (6 - s)];
            float2* p0 = &sl[lane * LROW + i0];
            float2 a = p0[0];
            float2 bw = cmulc(p0[half], w);
            p0[0]    = cadd(a, bw);
            p0[half] = csub(a, bw);
        }
        __syncthreads();
    }
    float4* dst = (float4*)(mesh + (size_t)xs * (NSZ * NSZ));
    for (int f = t; f < 8192; f += 1024) {
        int y = f >> 6, z = (f & 63) * 2;
        float2 u0 = sl[y * LROW + z], u1 = sl[y * LROW + z + 1];
        dst[f] = make_float4(u0.x, u0.y, u1.x, u1.y);
    }
}

// ---------- gather: mesh -> per-atom potential (2 channels) ----------

__global__ void gather_kernel(const float* __restrict__ pos,
                              const float* __restrict__ cell,
                              const float2* __restrict__ mesh,
                              const int* __restrict__ perm, int use_perm,
                              float* __restrict__ out,
                              int n_atoms) {
    int i = blockIdx.x * blockDim.x + threadIdx.x;
    if (i >= n_atoms) return;
    int a = use_perm ? perm[i] : i;
    int base[3];
    float w[3][4];
    stencil_raw(pos, cell, a, base, w);
    float acc0 = 0.0f, acc1 = 0.0f;
#pragma unroll
    for (int l = 0; l < 4; l++) {
        int gx = (base[0] + l - 1 + NSZ) & (NSZ - 1);
#pragma unroll
        for (int m = 0; m < 4; m++) {
            int gy = (base[1] + m - 1 + NSZ) & (NSZ - 1);
            float wlm = w[0][l] * w[1][m];
            int rowb = (gx * NSZ + gy) * NSZ;
#pragma unroll
            for (int n = 0; n < 4; n++) {
                int gz = (base[2] + n - 1 + NSZ) & (NSZ - 1);
                float2 v = mesh[rowb + gz];
                float ww = wlm * w[2][n];
                acc0 += ww * v.x;
                acc1 += ww * v.y;
            }
        }
    }
    out[(size_t)a * 2 + 0] = acc0;
    out[(size_t)a * 2 + 1] = acc1;
}

// ---------- launch ----------

extern "C" void kernel_launch(void* const* d_in, const int* in_sizes, int n_in,
                              void* d_out, int out_size, void* d_ws, size_t ws_size,
                              hipStream_t stream) {
    const float* pos     = (const float*)d_in[0];
    const float* cell    = (const float*)d_in[1];
    const int*   species = (const int*)d_in[2];
    int n_atoms = in_sizes[0] / 3;

    // workspace layout
    char* ws = (char*)d_ws;
    float2* mesh = (float2*)ws;                                   // 16 MiB
    size_t off = (size_t)NS3 * sizeof(float2);
    int* counts = (int*)(ws + off);           off += NBUCK * 4;
    int* starts = (int*)(ws + off);           off += (NBUCK + 4) * 4;
    int* cursor = (int*)(ws + off);           off += NBUCK * 4;
    int* ba     = (int*)(ws + off);           off += (size_t)n_atoms * 4;
    int* perm   = (int*)(ws + off);           off += (size_t)n_atoms * 4;
    bool binned = (ws_size >= off);

    // allow >64KB dynamic LDS for the fused FFT kernels
    hipFuncSetAttribute((const void*)fft_fwd_zy, hipFuncAttributeMaxDynamicSharedMemorySize, (int)LDS_BYTES);
    hipFuncSetAttribute((const void*)fft_x_g,    hipFuncAttributeMaxDynamicSharedMemorySize, (int)LDS_BYTES);
    hipFuncSetAttribute((const void*)fft_inv_yz, hipFuncAttributeMaxDynamicSharedMemorySize, (int)LDS_BYTES);

    int ab = (n_atoms + 255) / 256;

    if (binned) {
        hipMemsetAsync(ws, 0, (size_t)NS3 * sizeof(float2) + NBUCK * 4, stream);
        bin_hist<<<ab, 256, 0, stream>>>(pos, cell, counts, ba, n_atoms);
        scan4096<<<1, 1024, 0, stream>>>(counts, starts, cursor);
        bin_permute<<<ab, 256, 0, stream>>>(ba, cursor, perm, n_atoms);
        dim3 cg(NBUCK_D / 2, NBUCK_D / 2, NBUCK_D / 2);
        for (int c = 0; c < 8; c++) {
            scatter_binned<<<cg, 256, 0, stream>>>(pos, cell, species, starts, perm,
                                                   mesh, (c >> 2) & 1, (c >> 1) & 1, c & 1);
        }
    } else {
        hipMemsetAsync(mesh, 0, (size_t)NS3 * sizeof(float2), stream);
        scatter_atomic<<<ab, 256, 0, stream>>>(pos, cell, species, (float*)mesh, n_atoms);
    }

    fft_fwd_zy<<<NSZ, 1024, LDS_BYTES, stream>>>(mesh);
    fft_x_g   <<<NSZ, 1024, LDS_BYTES, stream>>>(mesh, cell, 1.0f /* SMEARING */);
    fft_inv_yz<<<NSZ, 1024, LDS_BYTES, stream>>>(mesh);

    gather_kernel<<<ab, 256, 0, stream>>>(pos, cell, mesh, perm, binned ? 1 : 0,
                                          (float*)d_out, n_atoms);
}

// Round 4
// 246.243 us; speedup vs baseline: 2.1759x; 1.1586x over previous
//
#include <hip/hip_runtime.h>

#define NSZ 128
#define NS3 (NSZ * NSZ * NSZ)
#define NBUCK_D 16           // buckets per dim (bucket = 8^3 cells)
#define NBUCK (NBUCK_D * NBUCK_D * NBUCK_D)
#define RGD 8                // region blocks per dim (region = 16^3 cells)
#define RW 16                // region width in cells
#define LROW 129             // padded LDS row stride (complex) for FFT planes
#define LDS_BYTES (NSZ * LROW * sizeof(float2))   // 132096

// ---------- small helpers ----------

__device__ __forceinline__ void inv3x3(const float* __restrict__ c, float* inv) {
    float a00 = c[0], a01 = c[1], a02 = c[2];
    float a10 = c[3], a11 = c[4], a12 = c[5];
    float a20 = c[6], a21 = c[7], a22 = c[8];
    float det = a00 * (a11 * a22 - a12 * a21)
              - a01 * (a10 * a22 - a12 * a20)
              + a02 * (a10 * a21 - a11 * a20);
    float id = 1.0f / det;
    inv[0] = (a11 * a22 - a12 * a21) * id;
    inv[1] = (a02 * a21 - a01 * a22) * id;
    inv[2] = (a01 * a12 - a02 * a11) * id;
    inv[3] = (a12 * a20 - a10 * a22) * id;
    inv[4] = (a00 * a22 - a02 * a20) * id;
    inv[5] = (a02 * a10 - a00 * a12) * id;
    inv[6] = (a10 * a21 - a11 * a20) * id;
    inv[7] = (a01 * a20 - a00 * a21) * id;
    inv[8] = (a00 * a11 - a01 * a10) * id;
}

__device__ __forceinline__ float det3x3(const float* __restrict__ c) {
    return c[0] * (c[4] * c[8] - c[5] * c[7])
         - c[1] * (c[3] * c[8] - c[5] * c[6])
         + c[2] * (c[3] * c[7] - c[4] * c[6]);
}

__device__ __forceinline__ int brev7(int i) { return (int)(__brev((unsigned)i) >> 25); }

__device__ __forceinline__ float2 cadd(float2 a, float2 b) { return make_float2(a.x + b.x, a.y + b.y); }
__device__ __forceinline__ float2 csub(float2 a, float2 b) { return make_float2(a.x - b.x, a.y - b.y); }
__device__ __forceinline__ float2 cmul(float2 a, float2 b) {
    return make_float2(a.x * b.x - a.y * b.y, a.x * b.y + a.y * b.x);
}
__device__ __forceinline__ float2 cmulc(float2 a, float2 b) {  // a * conj(b)
    return make_float2(a.x * b.x + a.y * b.y, a.y * b.x - a.x * b.y);
}

// order-4 stencil from a position (base clamped to [0,127]) + separable weights
__device__ __forceinline__ void stencil_pos(float px, float py, float pz,
                                            const float* __restrict__ inv,
                                            int base[3], float w[3][4]) {
    float pr[3];
    pr[0] = (float)NSZ * (px * inv[0] + py * inv[3] + pz * inv[6]);
    pr[1] = (float)NSZ * (px * inv[1] + py * inv[4] + pz * inv[7]);
    pr[2] = (float)NSZ * (px * inv[2] + py * inv[5] + pz * inv[8]);
#pragma unroll
    for (int d = 0; d < 3; d++) {
        float b = floorf(pr[d]);
        float x = pr[d] - b - 0.5f;
        float x2 = x * x, x3 = x2 * x;
        w[d][0] = (1.0f - 6.0f * x + 12.0f * x2 - 8.0f * x3) * (1.0f / 48.0f);
        w[d][1] = (23.0f - 30.0f * x - 12.0f * x2 + 24.0f * x3) * (1.0f / 48.0f);
        w[d][2] = (23.0f + 30.0f * x - 12.0f * x2 - 24.0f * x3) * (1.0f / 48.0f);
        w[d][3] = (1.0f + 6.0f * x + 12.0f * x2 + 8.0f * x3) * (1.0f / 48.0f);
        int bi = (int)b;
        base[d] = bi < 0 ? 0 : (bi > NSZ - 1 ? NSZ - 1 : bi);
    }
}

__device__ __forceinline__ int bucket_of(float px, float py, float pz,
                                         const float* __restrict__ inv) {
    float prx = (float)NSZ * (px * inv[0] + py * inv[3] + pz * inv[6]);
    float pry = (float)NSZ * (px * inv[1] + py * inv[4] + pz * inv[7]);
    float prz = (float)NSZ * (px * inv[2] + py * inv[5] + pz * inv[8]);
    int bx = (int)floorf(prx); bx = bx < 0 ? 0 : (bx > NSZ - 1 ? NSZ - 1 : bx);
    int by = (int)floorf(pry); by = by < 0 ? 0 : (by > NSZ - 1 ? NSZ - 1 : by);
    int bz = (int)floorf(prz); bz = bz < 0 ? 0 : (bz > NSZ - 1 ? NSZ - 1 : bz);
    return ((bx >> 3) * NBUCK_D + (by >> 3)) * NBUCK_D + (bz >> 3);
}

// ---------- binning ----------

__global__ void bin_hist(const float* __restrict__ pos, const float* __restrict__ cell,
                         int* __restrict__ counts, int n_atoms) {
    int a = blockIdx.x * blockDim.x + threadIdx.x;
    if (a >= n_atoms) return;
    float inv[9];
    inv3x3(cell, inv);
    atomicAdd(&counts[bucket_of(pos[a * 3], pos[a * 3 + 1], pos[a * 3 + 2], inv)], 1);
}

__global__ void __launch_bounds__(1024)
scan4096(const int* __restrict__ counts, int* __restrict__ starts, int* __restrict__ cursor) {
    __shared__ int wsum[16];
    __shared__ int wpref[16];
    int t = threadIdx.x;
    int c0 = counts[4 * t], c1 = counts[4 * t + 1], c2 = counts[4 * t + 2], c3 = counts[4 * t + 3];
    int tot = c0 + c1 + c2 + c3;
    int lane = t & 63, w = t >> 6;
    int incl = tot;
#pragma unroll
    for (int o = 1; o < 64; o <<= 1) {
        int v = __shfl_up(incl, o, 64);
        if (lane >= o) incl += v;
    }
    if (lane == 63) wsum[w] = incl;
    __syncthreads();
    if (t < 16) {
        int v = wsum[t], p = 0;
        for (int i = 0; i < 16; i++) { if (i < t) p += wsum[i]; }
        wpref[t] = p;
        (void)v;
    }
    __syncthreads();
    int ex = wpref[w] + incl - tot;
    starts[4 * t]     = ex;           cursor[4 * t]     = ex;
    starts[4 * t + 1] = ex + c0;      cursor[4 * t + 1] = ex + c0;
    starts[4 * t + 2] = ex + c0 + c1; cursor[4 * t + 2] = ex + c0 + c1;
    starts[4 * t + 3] = ex + c0 + c1 + c2; cursor[4 * t + 3] = ex + c0 + c1 + c2;
    if (t == 1023) starts[4096] = ex + tot;
}

// write sorted records: (px, py, pz, packed = (atom_id<<1)|species)
__global__ void bin_permute(const float* __restrict__ pos, const float* __restrict__ cell,
                            const int* __restrict__ species, int* __restrict__ cursor,
                            float4* __restrict__ recs, int n_atoms) {
    int a = blockIdx.x * blockDim.x + threadIdx.x;
    if (a >= n_atoms) return;
    float inv[9];
    inv3x3(cell, inv);
    float px = pos[a * 3], py = pos[a * 3 + 1], pz = pos[a * 3 + 2];
    int b = bucket_of(px, py, pz, inv);
    int p = atomicAdd(&cursor[b], 1);
    recs[p] = make_float4(px, py, pz, __int_as_float((a << 1) | (species[a] & 1)));
}

// ---------- one-shot region-owned scatter ----------
// Each block owns a 16^3 mesh region; gathers stencil contributions from atoms
// in the 4^3 neighborhood of 8^3 buckets; accumulates in LDS; pure-writes out.

#define ACC_ROW 33                      // padded row: 16 z * 2 species + 1
#define ACC_SZ (RW * RW * ACC_ROW)      // 8448 floats

__global__ void __launch_bounds__(256)
scatter_region(const float* __restrict__ cell, const int* __restrict__ starts,
               const float4* __restrict__ recs, float2* __restrict__ mesh) {
    __shared__ float acc[ACC_SZ];
    __shared__ int rstart_s[64];
    __shared__ int rpref_s[64];
    __shared__ int rtot_s;
    int t = threadIdx.x;
    int BX = blockIdx.x, BY = blockIdx.y, BZ = blockIdx.z;

    for (int i = t; i < ACC_SZ; i += 256) acc[i] = 0.0f;

    if (t < 64) {
        int dx = (t >> 4) & 3, dy = (t >> 2) & 3, dz = t & 3;
        int bx = (2 * BX - 1 + dx) & (NBUCK_D - 1);
        int by = (2 * BY - 1 + dy) & (NBUCK_D - 1);
        int bz = (2 * BZ - 1 + dz) & (NBUCK_D - 1);
        int b = (bx * NBUCK_D + by) * NBUCK_D + bz;
        int s0 = starts[b];
        int c = starts[b + 1] - s0;
        rstart_s[t] = s0;
        int incl = c;
#pragma unroll
        for (int o = 1; o < 64; o <<= 1) {
            int v = __shfl_up(incl, o, 64);
            if (t >= o) incl += v;
        }
        rpref_s[t] = incl - c;
        if (t == 63) rtot_s = incl;
    }
    __syncthreads();

    float inv[9];
    inv3x3(cell, inv);
    int M = rtot_s;
    int sx = BX << 4, sy = BY << 4, sz = BZ << 4;
    int lane = t & 63;

    for (int i = t; i < M; i += 256) {
        int r = 0;
#pragma unroll
        for (int step = 32; step; step >>= 1)
            if (r + step < 64 && rpref_s[r + step] <= i) r += step;
        float4 rec = recs[rstart_s[r] + (i - rpref_s[r])];
        int base[3];
        float w[3][4];
        stencil_pos(rec.x, rec.y, rec.z, inv, base, w);
        int rbx = (base[0] - sx + 2) & (NSZ - 1);
        int rby = (base[1] - sy + 2) & (NSZ - 1);
        int rbz = (base[2] - sz + 2) & (NSZ - 1);
        if (rbx >= 19 || rby >= 19 || rbz >= 19) continue;
        rbx -= 2; rby -= 2; rbz -= 2;
        int sp = __float_as_int(rec.w) & 1;
#pragma unroll
        for (int l = 0; l < 4; l++) {
            int cx = rbx + l - 1;
            if ((unsigned)cx >= (unsigned)RW) continue;
            float wl = w[0][l];
#pragma unroll
            for (int m = 0; m < 4; m++) {
                int cy = rby + m - 1;
                if ((unsigned)cy >= (unsigned)RW) continue;
                float wlm = wl * w[1][m];
                int rowb = (cx * RW + cy) * ACC_ROW + sp;
#pragma unroll
                for (int nn = 0; nn < 4; nn++) {
                    int n = (nn + lane) & 3;           // lane-rotated to spread atomics
                    int cz = rbz + n - 1;
                    if ((unsigned)cz >= (unsigned)RW) continue;
                    atomicAdd(&acc[rowb + cz * 2], wlm * w[2][n]);
                }
            }
        }
    }
    __syncthreads();

    // pure write of the owned region (every mesh cell written exactly once)
    for (int i = t; i < RW * RW * RW; i += 256) {
        int x = i >> 8, y = (i >> 4) & 15, z = i & 15;
        float2 v = make_float2(acc[(x * RW + y) * ACC_ROW + z * 2],
                               acc[(x * RW + y) * ACC_ROW + z * 2 + 1]);
        size_t gi = (size_t)((sx + x) * NSZ + (sy + y)) * NSZ + (sz + z);
        mesh[gi] = v;
    }
}

// ---------- fallback atomic scatter (if ws too small) ----------

__global__ void scatter_atomic(const float* __restrict__ pos,
                               const float* __restrict__ cell,
                               const int* __restrict__ species,
                               float* __restrict__ meshf, int n_atoms) {
    int a = blockIdx.x * blockDim.x + threadIdx.x;
    if (a >= n_atoms) return;
    float inv[9];
    inv3x3(cell, inv);
    int base[3];
    float w[3][4];
    stencil_pos(pos[a * 3], pos[a * 3 + 1], pos[a * 3 + 2], inv, base, w);
    int sp = species[a] & 1;
#pragma unroll
    for (int l = 0; l < 4; l++) {
        int gx = (base[0] + l - 1 + NSZ) & (NSZ - 1);
#pragma unroll
        for (int m = 0; m < 4; m++) {
            int gy = (base[1] + m - 1 + NSZ) & (NSZ - 1);
            float wlm = w[0][l] * w[1][m];
            int rowb = (gx * NSZ + gy) * NSZ;
#pragma unroll
            for (int n = 0; n < 4; n++) {
                int gz = (base[2] + n - 1 + NSZ) & (NSZ - 1);
                atomicAdd(meshf + (((size_t)(rowb + gz)) << 1) + sp, wlm * w[2][n]);
            }
        }
    }
}

// ---------- fused FFT kernels (unchanged from round 3, verified) ----------

__global__ void __launch_bounds__(1024)
fft_fwd_zy(float2* __restrict__ mesh) {
    extern __shared__ float2 sl[];
    __shared__ float2 tw[64];
    int t = threadIdx.x;
    int xs = blockIdx.x;
    if (t < 64) {
        float sn, cs;
        __sincosf(6.283185307179586f * (float)t / 128.0f, &sn, &cs);
        tw[t] = make_float2(cs, -sn);
    }
    const float4* src = (const float4*)(mesh + (size_t)xs * (NSZ * NSZ));
    for (int f = t; f < 8192; f += 1024) {
        float4 v = src[f];
        int y = f >> 6, z = (f & 63) * 2;
        sl[y * LROW + z]     = make_float2(v.x, v.y);
        sl[y * LROW + z + 1] = make_float2(v.z, v.w);
    }
    __syncthreads();
    int lane = t & 127, jb = (t >> 7) * 8;
    for (int s = 6; s >= 0; --s) {
        int half = 1 << s;
        for (int j = jb; j < jb + 8; ++j) {
            int pos = j & (half - 1);
            int i0 = ((j >> s) << (s + 1)) + pos;
            float2 w = tw[pos << (6 - s)];
            float2* p0 = &sl[lane * LROW + i0];
            float2 a = p0[0], b = p0[half];
            p0[0]    = cadd(a, b);
            p0[half] = cmul(csub(a, b), w);
        }
        __syncthreads();
    }
    for (int s = 6; s >= 0; --s) {
        int half = 1 << s;
        for (int j = jb; j < jb + 8; ++j) {
            int pos = j & (half - 1);
            int i0 = ((j >> s) << (s + 1)) + pos;
            float2 w = tw[pos << (6 - s)];
            float2* p0 = &sl[i0 * LROW + lane];
            float2 a = p0[0], b = p0[half * LROW];
            p0[0]           = cadd(a, b);
            p0[half * LROW] = cmul(csub(a, b), w);
        }
        __syncthreads();
    }
    float4* dst = (float4*)(mesh + (size_t)xs * (NSZ * NSZ));
    for (int f = t; f < 8192; f += 1024) {
        int y = f >> 6, z = (f & 63) * 2;
        float2 u0 = sl[y * LROW + z], u1 = sl[y * LROW + z + 1];
        dst[f] = make_float4(u0.x, u0.y, u1.x, u1.y);
    }
}

__global__ void __launch_bounds__(1024)
fft_x_g(float2* __restrict__ mesh, const float* __restrict__ cell, float smearing) {
    extern __shared__ float2 sl[];
    __shared__ float2 tw[64];
    int t = threadIdx.x;
    int y = blockIdx.x;
    if (t < 64) {
        float sn, cs;
        __sincosf(6.283185307179586f * (float)t / 128.0f, &sn, &cs);
        tw[t] = make_float2(cs, -sn);
    }
    for (int f = t; f < 8192; f += 1024) {
        int x = f >> 6, c = f & 63;
        float4 v = ((const float4*)mesh)[(size_t)x * 8192 + (size_t)y * 64 + c];
        int z = c * 2;
        sl[x * LROW + z]     = make_float2(v.x, v.y);
        sl[x * LROW + z + 1] = make_float2(v.z, v.w);
    }
    __syncthreads();
    int lane = t & 127, jb = (t >> 7) * 8;
    for (int s = 6; s >= 0; --s) {
        int half = 1 << s;
        for (int j = jb; j < jb + 8; ++j) {
            int pos = j & (half - 1);
            int i0 = ((j >> s) << (s + 1)) + pos;
            float2 w = tw[pos << (6 - s)];
            float2* p0 = &sl[i0 * LROW + lane];
            float2 a = p0[0], b = p0[half * LROW];
            p0[0]           = cadd(a, b);
            p0[half * LROW] = cmul(csub(a, b), w);
        }
        __syncthreads();
    }
    {
        float inv[9];
        inv3x3(cell, inv);
        float vol = fabsf(det3x3(cell));
        int kyi = brev7(y);
        float fy = (kyi < NSZ / 2) ? (float)kyi : (float)(kyi - NSZ);
        const float twopi = 6.283185307179586f;
        for (int f = t; f < NSZ * NSZ; f += 1024) {
            int px = f >> 7, pz = f & 127;
            int kxi = brev7(px), kzi = brev7(pz);
            float fx = (kxi < NSZ / 2) ? (float)kxi : (float)(kxi - NSZ);
            float fz = (kzi < NSZ / 2) ? (float)kzi : (float)(kzi - NSZ);
            float k0 = twopi * (fx * inv[0] + fy * inv[1] + fz * inv[2]);
            float k1 = twopi * (fx * inv[3] + fy * inv[4] + fz * inv[5]);
            float k2 = twopi * (fx * inv[6] + fy * inv[7] + fz * inv[8]);
            float ksq = k0 * k0 + k1 * k1 + k2 * k2;
            float g = 0.0f;
            if (ksq > 0.0f) {
                g = 12.566370614359172f * __expf(-0.5f * smearing * smearing * ksq) / ksq;
            }
            g /= vol;
            float2 v = sl[px * LROW + pz];
            sl[px * LROW + pz] = make_float2(v.x * g, v.y * g);
        }
    }
    __syncthreads();
    for (int s = 0; s < 7; ++s) {
        int half = 1 << s;
        for (int j = jb; j < jb + 8; ++j) {
            int pos = j & (half - 1);
            int i0 = ((j >> s) << (s + 1)) + pos;
            float2 w = tw[pos << (6 - s)];
            float2* p0 = &sl[i0 * LROW + lane];
            float2 a = p0[0];
            float2 bw = cmulc(p0[half * LROW], w);
            p0[0]           = cadd(a, bw);
            p0[half * LROW] = csub(a, bw);
        }
        __syncthreads();
    }
    for (int f = t; f < 8192; f += 1024) {
        int x = f >> 6, c = f & 63;
        int z = c * 2;
        float2 u0 = sl[x * LROW + z], u1 = sl[x * LROW + z + 1];
        ((float4*)mesh)[(size_t)x * 8192 + (size_t)y * 64 + c] = make_float4(u0.x, u0.y, u1.x, u1.y);
    }
}

__global__ void __launch_bounds__(1024)
fft_inv_yz(float2* __restrict__ mesh) {
    extern __shared__ float2 sl[];
    __shared__ float2 tw[64];
    int t = threadIdx.x;
    int xs = blockIdx.x;
    if (t < 64) {
        float sn, cs;
        __sincosf(6.283185307179586f * (float)t / 128.0f, &sn, &cs);
        tw[t] = make_float2(cs, -sn);
    }
    const float4* src = (const float4*)(mesh + (size_t)xs * (NSZ * NSZ));
    for (int f = t; f < 8192; f += 1024) {
        float4 v = src[f];
        int y = f >> 6, z = (f & 63) * 2;
        sl[y * LROW + z]     = make_float2(v.x, v.y);
        sl[y * LROW + z + 1] = make_float2(v.z, v.w);
    }
    __syncthreads();
    int lane = t & 127, jb = (t >> 7) * 8;
    for (int s = 0; s < 7; ++s) {
        int half = 1 << s;
        for (int j = jb; j < jb + 8; ++j) {
            int pos = j & (half - 1);
            int i0 = ((j >> s) << (s + 1)) + pos;
            float2 w = tw[pos << (6 - s)];
            float2* p0 = &sl[i0 * LROW + lane];
            float2 a = p0[0];
            float2 bw = cmulc(p0[half * LROW], w);
            p0[0]           = cadd(a, bw);
            p0[half * LROW] = csub(a, bw);
        }
        __syncthreads();
    }
    for (int s = 0; s < 7; ++s) {
        int half = 1 << s;
        for (int j = jb; j < jb + 8; ++j) {
            int pos = j & (half - 1);
            int i0 = ((j >> s) << (s + 1)) + pos;
            float2 w = tw[pos << (6 - s)];
            float2* p0 = &sl[lane * LROW + i0];
            float2 a = p0[0];
            float2 bw = cmulc(p0[half], w);
            p0[0]    = cadd(a, bw);
            p0[half] = csub(a, bw);
        }
        __syncthreads();
    }
    float4* dst = (float4*)(mesh + (size_t)xs * (NSZ * NSZ));
    for (int f = t; f < 8192; f += 1024) {
        int y = f >> 6, z = (f & 63) * 2;
        float2 u0 = sl[y * LROW + z], u1 = sl[y * LROW + z + 1];
        dst[f] = make_float4(u0.x, u0.y, u1.x, u1.y);
    }
}

// ---------- gather: mesh -> per-atom potential (2 channels) ----------

__global__ void gather_sorted(const float* __restrict__ cell,
                              const float2* __restrict__ mesh,
                              const float4* __restrict__ recs,
                              float2* __restrict__ out, int n_atoms) {
    int i = blockIdx.x * blockDim.x + threadIdx.x;
    if (i >= n_atoms) return;
    float4 rec = recs[i];
    float inv[9];
    inv3x3(cell, inv);
    int base[3];
    float w[3][4];
    stencil_pos(rec.x, rec.y, rec.z, inv, base, w);
    float acc0 = 0.0f, acc1 = 0.0f;
#pragma unroll
    for (int l = 0; l < 4; l++) {
        int gx = (base[0] + l - 1 + NSZ) & (NSZ - 1);
#pragma unroll
        for (int m = 0; m < 4; m++) {
            int gy = (base[1] + m - 1 + NSZ) & (NSZ - 1);
            float wlm = w[0][l] * w[1][m];
            int rowb = (gx * NSZ + gy) * NSZ;
#pragma unroll
            for (int n = 0; n < 4; n++) {
                int gz = (base[2] + n - 1 + NSZ) & (NSZ - 1);
                float2 v = mesh[rowb + gz];
                float ww = wlm * w[2][n];
                acc0 += ww * v.x;
                acc1 += ww * v.y;
            }
        }
    }
    out[__float_as_int(rec.w) >> 1] = make_float2(acc0, acc1);
}

__global__ void gather_plain(const float* __restrict__ pos,
                             const float* __restrict__ cell,
                             const float2* __restrict__ mesh,
                             float2* __restrict__ out, int n_atoms) {
    int a = blockIdx.x * blockDim.x + threadIdx.x;
    if (a >= n_atoms) return;
    float inv[9];
    inv3x3(cell, inv);
    int base[3];
    float w[3][4];
    stencil_pos(pos[a * 3], pos[a * 3 + 1], pos[a * 3 + 2], inv, base, w);
    float acc0 = 0.0f, acc1 = 0.0f;
#pragma unroll
    for (int l = 0; l < 4; l++) {
        int gx = (base[0] + l - 1 + NSZ) & (NSZ - 1);
#pragma unroll
        for (int m = 0; m < 4; m++) {
            int gy = (base[1] + m - 1 + NSZ) & (NSZ - 1);
            float wlm = w[0][l] * w[1][m];
            int rowb = (gx * NSZ + gy) * NSZ;
#pragma unroll
            for (int n = 0; n < 4; n++) {
                int gz = (base[2] + n - 1 + NSZ) & (NSZ - 1);
                float2 v = mesh[rowb + gz];
                float ww = wlm * w[2][n];
                acc0 += ww * v.x;
                acc1 += ww * v.y;
            }
        }
    }
    out[a] = make_float2(acc0, acc1);
}

// ---------- launch ----------

extern "C" void kernel_launch(void* const* d_in, const int* in_sizes, int n_in,
                              void* d_out, int out_size, void* d_ws, size_t ws_size,
                              hipStream_t stream) {
    const float* pos     = (const float*)d_in[0];
    const float* cell    = (const float*)d_in[1];
    const int*   species = (const int*)d_in[2];
    int n_atoms = in_sizes[0] / 3;

    // workspace layout
    char* ws = (char*)d_ws;
    float2* mesh = (float2*)ws;                                   // 16 MiB
    size_t off = (size_t)NS3 * sizeof(float2);
    int* counts = (int*)(ws + off);           off += NBUCK * 4;
    int* starts = (int*)(ws + off);           off += (NBUCK + 4) * 4;
    int* cursor = (int*)(ws + off);           off += NBUCK * 4;
    off = (off + 15) & ~(size_t)15;
    float4* recs = (float4*)(ws + off);       off += (size_t)n_atoms * 16;
    bool binned = (ws_size >= off);

    hipFuncSetAttribute((const void*)fft_fwd_zy, hipFuncAttributeMaxDynamicSharedMemorySize, (int)LDS_BYTES);
    hipFuncSetAttribute((const void*)fft_x_g,    hipFuncAttributeMaxDynamicSharedMemorySize, (int)LDS_BYTES);
    hipFuncSetAttribute((const void*)fft_inv_yz, hipFuncAttributeMaxDynamicSharedMemorySize, (int)LDS_BYTES);

    int ab = (n_atoms + 255) / 256;

    if (binned) {
        hipMemsetAsync(counts, 0, NBUCK * 4, stream);
        bin_hist<<<ab, 256, 0, stream>>>(pos, cell, counts, n_atoms);
        scan4096<<<1, 1024, 0, stream>>>(counts, starts, cursor);
        bin_permute<<<ab, 256, 0, stream>>>(pos, cell, species, cursor, recs, n_atoms);
        dim3 rg(RGD, RGD, RGD);
        scatter_region<<<rg, 256, 0, stream>>>(cell, starts, recs, mesh);
    } else {
        hipMemsetAsync(mesh, 0, (size_t)NS3 * sizeof(float2), stream);
        scatter_atomic<<<ab, 256, 0, stream>>>(pos, cell, species, (float*)mesh, n_atoms);
    }

    fft_fwd_zy<<<NSZ, 1024, LDS_BYTES, stream>>>(mesh);
    fft_x_g   <<<NSZ, 1024, LDS_BYTES, stream>>>(mesh, cell, 1.0f /* SMEARING */);
    fft_inv_yz<<<NSZ, 1024, LDS_BYTES, stream>>>(mesh);

    if (binned) {
        gather_sorted<<<ab, 256, 0, stream>>>(cell, mesh, recs, (float2*)d_out, n_atoms);
    } else {
        gather_plain<<<ab, 256, 0, stream>>>(pos, cell, mesh, (float2*)d_out, n_atoms);
    }
}

// Round 7
// 232.840 us; speedup vs baseline: 2.3011x; 1.0576x over previous
//
#include <hip/hip_runtime.h>

#define NSZ 128
#define NS3 (NSZ * NSZ * NSZ)
#define NBUCK_D 16           // buckets per dim (bucket = 8^3 cells)
#define NBUCK (NBUCK_D * NBUCK_D * NBUCK_D)
#define RGD 8                // region blocks per dim (region = 16^3 cells)
#define RW 16                // region width in cells
#define LROW 129             // padded LDS row stride (complex) for FFT planes
#define LDS_BYTES (NSZ * LROW * sizeof(float2))   // 132096

// ---------- small helpers ----------

__device__ __forceinline__ void inv3x3(const float* __restrict__ c, float* inv) {
    float a00 = c[0], a01 = c[1], a02 = c[2];
    float a10 = c[3], a11 = c[4], a12 = c[5];
    float a20 = c[6], a21 = c[7], a22 = c[8];
    float det = a00 * (a11 * a22 - a12 * a21)
              - a01 * (a10 * a22 - a12 * a20)
              + a02 * (a10 * a21 - a11 * a20);
    float id = 1.0f / det;
    inv[0] = (a11 * a22 - a12 * a21) * id;
    inv[1] = (a02 * a21 - a01 * a22) * id;
    inv[2] = (a01 * a12 - a02 * a11) * id;
    inv[3] = (a12 * a20 - a10 * a22) * id;
    inv[4] = (a00 * a22 - a02 * a20) * id;
    inv[5] = (a02 * a10 - a00 * a12) * id;
    inv[6] = (a10 * a21 - a11 * a20) * id;
    inv[7] = (a01 * a20 - a00 * a21) * id;
    inv[8] = (a00 * a11 - a01 * a10) * id;
}

__device__ __forceinline__ float det3x3(const float* __restrict__ c) {
    return c[0] * (c[4] * c[8] - c[5] * c[7])
         - c[1] * (c[3] * c[8] - c[5] * c[6])
         + c[2] * (c[3] * c[7] - c[4] * c[6]);
}

__device__ __forceinline__ int brev7(int i) { return (int)(__brev((unsigned)i) >> 25); }

__device__ __forceinline__ float2 cadd(float2 a, float2 b) { return make_float2(a.x + b.x, a.y + b.y); }
__device__ __forceinline__ float2 csub(float2 a, float2 b) { return make_float2(a.x - b.x, a.y - b.y); }
__device__ __forceinline__ float2 cmul(float2 a, float2 b) {
    return make_float2(a.x * b.x - a.y * b.y, a.x * b.y + a.y * b.x);
}
__device__ __forceinline__ float2 cmulc(float2 a, float2 b) {  // a * conj(b)
    return make_float2(a.x * b.x + a.y * b.y, a.y * b.x - a.x * b.y);
}

// fractional mesh coords -> per-dim base (clamped) ; weights computed separately
__device__ __forceinline__ void bases_of(float px, float py, float pz,
                                         const float* __restrict__ inv,
                                         int base[3], float frac[3]) {
    float pr[3];
    pr[0] = (float)NSZ * (px * inv[0] + py * inv[3] + pz * inv[6]);
    pr[1] = (float)NSZ * (px * inv[1] + py * inv[4] + pz * inv[7]);
    pr[2] = (float)NSZ * (px * inv[2] + py * inv[5] + pz * inv[8]);
#pragma unroll
    for (int d = 0; d < 3; d++) {
        float b = floorf(pr[d]);
        frac[d] = pr[d] - b - 0.5f;
        int bi = (int)b;
        base[d] = bi < 0 ? 0 : (bi > NSZ - 1 ? NSZ - 1 : bi);
    }
}

__device__ __forceinline__ void weights_of(float x, float w[4]) {
    float x2 = x * x, x3 = x2 * x;
    w[0] = (1.0f - 6.0f * x + 12.0f * x2 - 8.0f * x3) * (1.0f / 48.0f);
    w[1] = (23.0f - 30.0f * x - 12.0f * x2 + 24.0f * x3) * (1.0f / 48.0f);
    w[2] = (23.0f + 30.0f * x - 12.0f * x2 - 24.0f * x3) * (1.0f / 48.0f);
    w[3] = (1.0f + 6.0f * x + 12.0f * x2 + 8.0f * x3) * (1.0f / 48.0f);
}

__device__ __forceinline__ void stencil_pos(float px, float py, float pz,
                                            const float* __restrict__ inv,
                                            int base[3], float w[3][4]) {
    float frac[3];
    bases_of(px, py, pz, inv, base, frac);
    weights_of(frac[0], w[0]);
    weights_of(frac[1], w[1]);
    weights_of(frac[2], w[2]);
}

__device__ __forceinline__ int bucket_of(float px, float py, float pz,
                                         const float* __restrict__ inv) {
    int base[3];
    float frac[3];
    bases_of(px, py, pz, inv, base, frac);
    return ((base[0] >> 3) * NBUCK_D + (base[1] >> 3)) * NBUCK_D + (base[2] >> 3);
}

// ---------- binning ----------

__global__ void bin_hist(const float* __restrict__ pos, const float* __restrict__ cell,
                         int* __restrict__ counts, int n_atoms) {
    int a = blockIdx.x * blockDim.x + threadIdx.x;
    if (a >= n_atoms) return;
    float inv[9];
    inv3x3(cell, inv);
    atomicAdd(&counts[bucket_of(pos[a * 3], pos[a * 3 + 1], pos[a * 3 + 2], inv)], 1);
}

__global__ void __launch_bounds__(1024)
scan4096(const int* __restrict__ counts, int* __restrict__ starts, int* __restrict__ cursor) {
    __shared__ int wsum[16];
    __shared__ int wpref[16];
    int t = threadIdx.x;
    int c0 = counts[4 * t], c1 = counts[4 * t + 1], c2 = counts[4 * t + 2], c3 = counts[4 * t + 3];
    int tot = c0 + c1 + c2 + c3;
    int lane = t & 63, w = t >> 6;
    int incl = tot;
#pragma unroll
    for (int o = 1; o < 64; o <<= 1) {
        int v = __shfl_up(incl, o, 64);
        if (lane >= o) incl += v;
    }
    if (lane == 63) wsum[w] = incl;
    __syncthreads();
    if (t < 16) {
        int p = 0;
        for (int i = 0; i < 16; i++) { if (i < t) p += wsum[i]; }
        wpref[t] = p;
    }
    __syncthreads();
    int ex = wpref[w] + incl - tot;
    starts[4 * t]     = ex;                cursor[4 * t]     = ex;
    starts[4 * t + 1] = ex + c0;           cursor[4 * t + 1] = ex + c0;
    starts[4 * t + 2] = ex + c0 + c1;      cursor[4 * t + 2] = ex + c0 + c1;
    starts[4 * t + 3] = ex + c0 + c1 + c2; cursor[4 * t + 3] = ex + c0 + c1 + c2;
    if (t == 1023) starts[4096] = ex + tot;
}

// write sorted records: (px, py, pz, packed = (atom_id<<1)|species)
__global__ void bin_permute(const float* __restrict__ pos, const float* __restrict__ cell,
                            const int* __restrict__ species, int* __restrict__ cursor,
                            float4* __restrict__ recs, int n_atoms) {
    int a = blockIdx.x * blockDim.x + threadIdx.x;
    if (a >= n_atoms) return;
    float inv[9];
    inv3x3(cell, inv);
    float px = pos[a * 3], py = pos[a * 3 + 1], pz = pos[a * 3 + 2];
    int b = bucket_of(px, py, pz, inv);
    int p = atomicAdd(&cursor[b], 1);
    recs[p] = make_float4(px, py, pz, __int_as_float((a << 1) | (species[a] & 1)));
}

// ---------- one-shot region-owned scatter (1024 threads, early clip) ----------

#define ACC_ROW 33                      // padded row: 16 z * 2 species + 1
#define ACC_SZ (RW * RW * ACC_ROW)      // 8448 floats

__global__ void __launch_bounds__(1024)
scatter_region(const float* __restrict__ cell, const int* __restrict__ starts,
               const float4* __restrict__ recs, float2* __restrict__ mesh) {
    __shared__ float acc[ACC_SZ];
    __shared__ int rstart_s[64];
    __shared__ int rpref_s[64];
    __shared__ int rtot_s;
    int t = threadIdx.x;
    int BX = blockIdx.x, BY = blockIdx.y, BZ = blockIdx.z;

    for (int i = t; i < ACC_SZ; i += 1024) acc[i] = 0.0f;

    if (t < 64) {
        int dx = (t >> 4) & 3, dy = (t >> 2) & 3, dz = t & 3;
        int bx = (2 * BX - 1 + dx) & (NBUCK_D - 1);
        int by = (2 * BY - 1 + dy) & (NBUCK_D - 1);
        int bz = (2 * BZ - 1 + dz) & (NBUCK_D - 1);
        int b = (bx * NBUCK_D + by) * NBUCK_D + bz;
        int s0 = starts[b];
        int c = starts[b + 1] - s0;
        rstart_s[t] = s0;
        int incl = c;
#pragma unroll
        for (int o = 1; o < 64; o <<= 1) {
            int v = __shfl_up(incl, o, 64);
            if (t >= o) incl += v;
        }
        rpref_s[t] = incl - c;
        if (t == 63) rtot_s = incl;
    }
    __syncthreads();

    float inv[9];
    inv3x3(cell, inv);
    int M = rtot_s;
    int sx = BX << 4, sy = BY << 4, sz = BZ << 4;
    int lane = t & 63;

    for (int i = t; i < M; i += 1024) {
        int r = 0;
#pragma unroll
        for (int step = 32; step; step >>= 1)
            if (r + step < 64 && rpref_s[r + step] <= i) r += step;
        float4 rec = recs[rstart_s[r] + (i - rpref_s[r])];
        int base[3];
        float frac[3];
        bases_of(rec.x, rec.y, rec.z, inv, base, frac);
        int rbx = (base[0] - sx + 2) & (NSZ - 1);
        int rby = (base[1] - sy + 2) & (NSZ - 1);
        int rbz = (base[2] - sz + 2) & (NSZ - 1);
        if (rbx >= 19 || rby >= 19 || rbz >= 19) continue;   // early clip: no weights yet
        rbx -= 2; rby -= 2; rbz -= 2;
        float w[3][4];
        weights_of(frac[0], w[0]);
        weights_of(frac[1], w[1]);
        weights_of(frac[2], w[2]);
        int sp = __float_as_int(rec.w) & 1;
#pragma unroll
        for (int l = 0; l < 4; l++) {
            int cx = rbx + l - 1;
            if ((unsigned)cx >= (unsigned)RW) continue;
            float wl = w[0][l];
#pragma unroll
            for (int m = 0; m < 4; m++) {
                int cy = rby + m - 1;
                if ((unsigned)cy >= (unsigned)RW) continue;
                float wlm = wl * w[1][m];
                int rowb = (cx * RW + cy) * ACC_ROW + sp;
#pragma unroll
                for (int nn = 0; nn < 4; nn++) {
                    int n = (nn + lane) & 3;           // lane-rotated to spread atomics
                    int cz = rbz + n - 1;
                    if ((unsigned)cz >= (unsigned)RW) continue;
                    atomicAdd(&acc[rowb + cz * 2], wlm * w[2][n]);
                }
            }
        }
    }
    __syncthreads();

    for (int i = t; i < RW * RW * RW; i += 1024) {
        int x = i >> 8, y = (i >> 4) & 15, z = i & 15;
        float2 v = make_float2(acc[(x * RW + y) * ACC_ROW + z * 2],
                               acc[(x * RW + y) * ACC_ROW + z * 2 + 1]);
        size_t gi = (size_t)((sx + x) * NSZ + (sy + y)) * NSZ + (sz + z);
        mesh[gi] = v;
    }
}

// ---------- fallback atomic scatter (if ws too small) ----------

__global__ void scatter_atomic(const float* __restrict__ pos,
                               const float* __restrict__ cell,
                               const int* __restrict__ species,
                               float* __restrict__ meshf, int n_atoms) {
    int a = blockIdx.x * blockDim.x + threadIdx.x;
    if (a >= n_atoms) return;
    float inv[9];
    inv3x3(cell, inv);
    int base[3];
    float w[3][4];
    stencil_pos(pos[a * 3], pos[a * 3 + 1], pos[a * 3 + 2], inv, base, w);
    int sp = species[a] & 1;
#pragma unroll
    for (int l = 0; l < 4; l++) {
        int gx = (base[0] + l - 1 + NSZ) & (NSZ - 1);
#pragma unroll
        for (int m = 0; m < 4; m++) {
            int gy = (base[1] + m - 1 + NSZ) & (NSZ - 1);
            float wlm = w[0][l] * w[1][m];
            int rowb = (gx * NSZ + gy) * NSZ;
#pragma unroll
            for (int n = 0; n < 4; n++) {
                int gz = (base[2] + n - 1 + NSZ) & (NSZ - 1);
                atomicAdd(meshf + (((size_t)(rowb + gz)) << 1) + sp, wlm * w[2][n]);
            }
        }
    }
}

// ---------- fused FFT kernels ----------

__global__ void __launch_bounds__(1024)
fft_fwd_zy(float2* __restrict__ mesh) {
    extern __shared__ float2 sl[];
    __shared__ float2 tw[64];
    int t = threadIdx.x;
    int xs = blockIdx.x;
    if (t < 64) {
        float sn, cs;
        __sincosf(6.283185307179586f * (float)t / 128.0f, &sn, &cs);
        tw[t] = make_float2(cs, -sn);
    }
    const float4* src = (const float4*)(mesh + (size_t)xs * (NSZ * NSZ));
    for (int f = t; f < 8192; f += 1024) {
        float4 v = src[f];
        int y = f >> 6, z = (f & 63) * 2;
        sl[y * LROW + z]     = make_float2(v.x, v.y);
        sl[y * LROW + z + 1] = make_float2(v.z, v.w);
    }
    __syncthreads();
    int lane = t & 127, jb = (t >> 7) * 8;
    for (int s = 6; s >= 0; --s) {
        int half = 1 << s;
        for (int j = jb; j < jb + 8; ++j) {
            int pos = j & (half - 1);
            int i0 = ((j >> s) << (s + 1)) + pos;
            float2 w = tw[pos << (6 - s)];
            float2* p0 = &sl[lane * LROW + i0];
            float2 a = p0[0], b = p0[half];
            p0[0]    = cadd(a, b);
            p0[half] = cmul(csub(a, b), w);
        }
        __syncthreads();
    }
    for (int s = 6; s >= 0; --s) {
        int half = 1 << s;
        for (int j = jb; j < jb + 8; ++j) {
            int pos = j & (half - 1);
            int i0 = ((j >> s) << (s + 1)) + pos;
            float2 w = tw[pos << (6 - s)];
            float2* p0 = &sl[i0 * LROW + lane];
            float2 a = p0[0], b = p0[half * LROW];
            p0[0]           = cadd(a, b);
            p0[half * LROW] = cmul(csub(a, b), w);
        }
        __syncthreads();
    }
    float4* dst = (float4*)(mesh + (size_t)xs * (NSZ * NSZ));
    for (int f = t; f < 8192; f += 1024) {
        int y = f >> 6, z = (f & 63) * 2;
        float2 u0 = sl[y * LROW + z], u1 = sl[y * LROW + z + 1];
        dst[f] = make_float4(u0.x, u0.y, u1.x, u1.y);
    }
}

__global__ void __launch_bounds__(1024)
fft_x_g(float2* __restrict__ mesh, const float* __restrict__ cell, float smearing) {
    extern __shared__ float2 sl[];
    __shared__ float2 tw[64];
    int t = threadIdx.x;
    int y = blockIdx.x;
    if (t < 64) {
        float sn, cs;
        __sincosf(6.283185307179586f * (float)t / 128.0f, &sn, &cs);
        tw[t] = make_float2(cs, -sn);
    }
    for (int f = t; f < 8192; f += 1024) {
        int x = f >> 6, c = f & 63;
        float4 v = ((const float4*)mesh)[(size_t)x * 8192 + (size_t)y * 64 + c];
        int z = c * 2;
        sl[x * LROW + z]     = make_float2(v.x, v.y);
        sl[x * LROW + z + 1] = make_float2(v.z, v.w);
    }
    __syncthreads();
    int lane = t & 127, jb = (t >> 7) * 8;
    for (int s = 6; s >= 0; --s) {
        int half = 1 << s;
        for (int j = jb; j < jb + 8; ++j) {
            int pos = j & (half - 1);
            int i0 = ((j >> s) << (s + 1)) + pos;
            float2 w = tw[pos << (6 - s)];
            float2* p0 = &sl[i0 * LROW + lane];
            float2 a = p0[0], b = p0[half * LROW];
            p0[0]           = cadd(a, b);
            p0[half * LROW] = cmul(csub(a, b), w);
        }
        __syncthreads();
    }
    {
        float inv[9];
        inv3x3(cell, inv);
        float vol = fabsf(det3x3(cell));
        int kyi = brev7(y);
        float fy = (kyi < NSZ / 2) ? (float)kyi : (float)(kyi - NSZ);
        const float twopi = 6.283185307179586f;
        for (int f = t; f < NSZ * NSZ; f += 1024) {
            int px = f >> 7, pz = f & 127;
            int kxi = brev7(px), kzi = brev7(pz);
            float fx = (kxi < NSZ / 2) ? (float)kxi : (float)(kxi - NSZ);
            float fz = (kzi < NSZ / 2) ? (float)kzi : (float)(kzi - NSZ);
            float k0 = twopi * (fx * inv[0] + fy * inv[1] + fz * inv[2]);
            float k1 = twopi * (fx * inv[3] + fy * inv[4] + fz * inv[5]);
            float k2 = twopi * (fx * inv[6] + fy * inv[7] + fz * inv[8]);
            float ksq = k0 * k0 + k1 * k1 + k2 * k2;
            float g = 0.0f;
            if (ksq > 0.0f) {
                g = 12.566370614359172f * __expf(-0.5f * smearing * smearing * ksq) / ksq;
            }
            g /= vol;
            float2 v = sl[px * LROW + pz];
            sl[px * LROW + pz] = make_float2(v.x * g, v.y * g);
        }
    }
    __syncthreads();
    for (int s = 0; s < 7; ++s) {
        int half = 1 << s;
        for (int j = jb; j < jb + 8; ++j) {
            int pos = j & (half - 1);
            int i0 = ((j >> s) << (s + 1)) + pos;
            float2 w = tw[pos << (6 - s)];
            float2* p0 = &sl[i0 * LROW + lane];
            float2 a = p0[0];
            float2 bw = cmulc(p0[half * LROW], w);
            p0[0]           = cadd(a, bw);
            p0[half * LROW] = csub(a, bw);
        }
        __syncthreads();
    }
    for (int f = t; f < 8192; f += 1024) {
        int x = f >> 6, c = f & 63;
        int z = c * 2;
        float2 u0 = sl[x * LROW + z], u1 = sl[x * LROW + z + 1];
        ((float4*)mesh)[(size_t)x * 8192 + (size_t)y * 64 + c] = make_float4(u0.x, u0.y, u1.x, u1.y);
    }
}

__global__ void __launch_bounds__(1024)
fft_inv_yz(float2* __restrict__ mesh) {
    extern __shared__ float2 sl[];
    __shared__ float2 tw[64];
    int t = threadIdx.x;
    int xs = blockIdx.x;
    if (t < 64) {
        float sn, cs;
        __sincosf(6.283185307179586f * (float)t / 128.0f, &sn, &cs);
        tw[t] = make_float2(cs, -sn);
    }
    const float4* src = (const float4*)(mesh + (size_t)xs * (NSZ * NSZ));
    for (int f = t; f < 8192; f += 1024) {
        float4 v = src[f];
        int y = f >> 6, z = (f & 63) * 2;
        sl[y * LROW + z]     = make_float2(v.x, v.y);
        sl[y * LROW + z + 1] = make_float2(v.z, v.w);
    }
    __syncthreads();
    int lane = t & 127, jb = (t >> 7) * 8;
    for (int s = 0; s < 7; ++s) {
        int half = 1 << s;
        for (int j = jb; j < jb + 8; ++j) {
            int pos = j & (half - 1);
            int i0 = ((j >> s) << (s + 1)) + pos;
            float2 w = tw[pos << (6 - s)];
            float2* p0 = &sl[i0 * LROW + lane];
            float2 a = p0[0];
            float2 bw = cmulc(p0[half * LROW], w);
            p0[0]           = cadd(a, bw);
            p0[half * LROW] = csub(a, bw);
        }
        __syncthreads();
    }
    for (int s = 0; s < 7; ++s) {
        int half = 1 << s;
        for (int j = jb; j < jb + 8; ++j) {
            int pos = j & (half - 1);
            int i0 = ((j >> s) << (s + 1)) + pos;
            float2 w = tw[pos << (6 - s)];
            float2* p0 = &sl[lane * LROW + i0];
            float2 a = p0[0];
            float2 bw = cmulc(p0[half], w);
            p0[0]    = cadd(a, bw);
            p0[half] = csub(a, bw);
        }
        __syncthreads();
    }
    float4* dst = (float4*)(mesh + (size_t)xs * (NSZ * NSZ));
    for (int f = t; f < 8192; f += 1024) {
        int y = f >> 6, z = (f & 63) * 2;
        float2 u0 = sl[y * LROW + z], u1 = sl[y * LROW + z + 1];
        dst[f] = make_float4(u0.x, u0.y, u1.x, u1.y);
    }
}

// ---------- gather: per-bucket LDS-staged, one thread per atom ----------

#define GROW 12   // padded z-row for gather LDS (11 used)

__global__ void __launch_bounds__(128)
gather_region(const float* __restrict__ cell, const int* __restrict__ starts,
              const float4* __restrict__ recs, const float2* __restrict__ mesh,
              float2* __restrict__ out) {
    __shared__ float2 gm[11 * 11 * GROW];
    int t = threadIdx.x;
    int b = blockIdx.x;
    int bx = b >> 8, by = (b >> 4) & 15, bz = b & 15;
    int ox = bx * 8 - 1, oy = by * 8 - 1, oz = bz * 8 - 1;

    // stage the bucket's 11^3 halo region (rows of 11 are contiguous in z)
    for (int i = t; i < 11 * 11 * 11; i += 128) {
        int x = i / 121, rem = i % 121, y = rem / 11, z = rem % 11;
        int gx = (ox + x) & (NSZ - 1);
        int gy = (oy + y) & (NSZ - 1);
        int gz = (oz + z) & (NSZ - 1);
        gm[(x * 11 + y) * GROW + z] = mesh[(size_t)(gx * NSZ + gy) * NSZ + gz];
    }
    __syncthreads();

    int s = starts[b], e = starts[b + 1];
    float inv[9];
    inv3x3(cell, inv);

    // one thread per atom; full 4^3 stencil from LDS
    for (int ai = s + t; ai < e; ai += 128) {
        float4 rec = recs[ai];
        int base[3];
        float w[3][4];
        stencil_pos(rec.x, rec.y, rec.z, inv, base, w);
        int lx0 = base[0] - bx * 8;   // in [0,7]; +l gives [0,10] with halo offset
        int ly0 = base[1] - by * 8;
        int lz0 = base[2] - bz * 8;
        float acc0 = 0.0f, acc1 = 0.0f;
#pragma unroll
        for (int l = 0; l < 4; l++) {
            float wl = w[0][l];
#pragma unroll
            for (int m = 0; m < 4; m++) {
                float wlm = wl * w[1][m];
                int rowb = ((lx0 + l) * 11 + (ly0 + m)) * GROW + lz0;
#pragma unroll
                for (int n = 0; n < 4; n++) {
                    float2 v = gm[rowb + n];
                    float ww = wlm * w[2][n];
                    acc0 += ww * v.x;
                    acc1 += ww * v.y;
                }
            }
        }
        out[__float_as_int(rec.w) >> 1] = make_float2(acc0, acc1);
    }
}

__global__ void gather_plain(const float* __restrict__ pos,
                             const float* __restrict__ cell,
                             const float2* __restrict__ mesh,
                             float2* __restrict__ out, int n_atoms) {
    int a = blockIdx.x * blockDim.x + threadIdx.x;
    if (a >= n_atoms) return;
    float inv[9];
    inv3x3(cell, inv);
    int base[3];
    float w[3][4];
    stencil_pos(pos[a * 3], pos[a * 3 + 1], pos[a * 3 + 2], inv, base, w);
    float acc0 = 0.0f, acc1 = 0.0f;
#pragma unroll
    for (int l = 0; l < 4; l++) {
        int gx = (base[0] + l - 1 + NSZ) & (NSZ - 1);
#pragma unroll
        for (int m = 0; m < 4; m++) {
            int gy = (base[1] + m - 1 + NSZ) & (NSZ - 1);
            float wlm = w[0][l] * w[1][m];
            int rowb = (gx * NSZ + gy) * NSZ;
#pragma unroll
            for (int n = 0; n < 4; n++) {
                int gz = (base[2] + n - 1 + NSZ) & (NSZ - 1);
                float2 v = mesh[rowb + gz];
                float ww = wlm * w[2][n];
                acc0 += ww * v.x;
                acc1 += ww * v.y;
            }
        }
    }
    out[a] = make_float2(acc0, acc1);
}

// ---------- launch ----------

extern "C" void kernel_launch(void* const* d_in, const int* in_sizes, int n_in,
                              void* d_out, int out_size, void* d_ws, size_t ws_size,
                              hipStream_t stream) {
    const float* pos     = (const float*)d_in[0];
    const float* cell    = (const float*)d_in[1];
    const int*   species = (const int*)d_in[2];
    int n_atoms = in_sizes[0] / 3;

    // workspace layout
    char* ws = (char*)d_ws;
    float2* mesh = (float2*)ws;                                   // 16 MiB
    size_t off = (size_t)NS3 * sizeof(float2);
    int* counts = (int*)(ws + off);           off += NBUCK * 4;
    int* starts = (int*)(ws + off);           off += (NBUCK + 4) * 4;
    int* cursor = (int*)(ws + off);           off += NBUCK * 4;
    off = (off + 15) & ~(size_t)15;
    float4* recs = (float4*)(ws + off);       off += (size_t)n_atoms * 16;
    bool binned = (ws_size >= off);

    hipFuncSetAttribute((const void*)fft_fwd_zy, hipFuncAttributeMaxDynamicSharedMemorySize, (int)LDS_BYTES);
    hipFuncSetAttribute((const void*)fft_x_g,    hipFuncAttributeMaxDynamicSharedMemorySize, (int)LDS_BYTES);
    hipFuncSetAttribute((const void*)fft_inv_yz, hipFuncAttributeMaxDynamicSharedMemorySize, (int)LDS_BYTES);

    int ab = (n_atoms + 255) / 256;

    if (binned) {
        hipMemsetAsync(counts, 0, NBUCK * 4, stream);
        bin_hist<<<ab, 256, 0, stream>>>(pos, cell, counts, n_atoms);
        scan4096<<<1, 1024, 0, stream>>>(counts, starts, cursor);
        bin_permute<<<ab, 256, 0, stream>>>(pos, cell, species, cursor, recs, n_atoms);
        dim3 rg(RGD, RGD, RGD);
        scatter_region<<<rg, 1024, 0, stream>>>(cell, starts, recs, mesh);
    } else {
        hipMemsetAsync(mesh, 0, (size_t)NS3 * sizeof(float2), stream);
        scatter_atomic<<<ab, 256, 0, stream>>>(pos, cell, species, (float*)mesh, n_atoms);
    }

    fft_fwd_zy<<<NSZ, 1024, LDS_BYTES, stream>>>(mesh);
    fft_x_g   <<<NSZ, 1024, LDS_BYTES, stream>>>(mesh, cell, 1.0f /* SMEARING */);
    fft_inv_yz<<<NSZ, 1024, LDS_BYTES, stream>>>(mesh);

    if (binned) {
        gather_region<<<NBUCK, 128, 0, stream>>>(cell, starts, recs, mesh, (float2*)d_out);
    } else {
        gather_plain<<<ab, 256, 0, stream>>>(pos, cell, mesh, (float2*)d_out, n_atoms);
    }
}